// Round 13
// baseline (504.896 us; speedup 1.0000x reference)
//
#include <hip/hip_runtime.h>
#include <math.h>

// FNO2d: B=8, CIN=2, COUT=1, W0=64, modes 16x16, NL=4, H=W=256
// h stored channels-last BF16: [B][H][W][64] ushort.
// Y  (F1 out, fp32): [B][H(x)][16ky][64c][2]
// Xfp (F2 out, fp32): 4 x-partials of Xf [B][64c][256m][2], m = kx*16+ky
// A2 (spec out, bf16): [B*256 rows][64o][32k'] -- separate region; must not
//    overlay Y (fused k_pw writes Y while other blocks still read A2).
// Trig  (bf16): [256y][32k'] (A-frags for k_pw I2)
// TrigT (bf16): [32 rows][256y] (A-frags for F1; rows 0-15 cos, 16-31 sin)
// k_f1 (layer 0 only) = input 1x1 conv + bf16 MFMA GEMM Y = TrigT @ H.
// k_pw = bf16 MFMA GEMM [H | Trig] @ [pw_w^T ; A2] + bias -> gelu -> hb,
//        FUSED with next layer's F1 via LDS (stage -> pw -> re-stage -> F1).
// k_out = bf16 MFMA GEMM (H @ o1^T) + gelu + cross-lane o2 dot.
//
// HARD-WON RULES:
//  - (R2/R3/R5) NEVER use min-waves arg of __launch_bounds__ with per-thread
//    accumulator arrays: backend spills to hit the VGPR tier.
//  - (R4/R6/R9) per-thread accs + uniform weight streaming via s_load is
//    latency-bound; keep weights in VGPR MFMA B-frags.
//  - (R11) grid must cover 256 CUs.  (R12) fuse pairs sharing a row tile.
//  - (R13) in-place kernels must stage the ENTIRE input tile (LDS or regs)
//    behind the first in-place write -- no direct global reads after.
//  - (R16) fast A-S-erf gelu REGRESSED (TRANS-pipe rcp+exp); erff kept.
//  - (R17) thin-grid latency kernels: k_f2 4-way x-split -> +19us.
//  - (R19) k_spec widened to 512 thr -> +7us.
//  - (R20) k_in->k_f1 and k_xsum->k_spec fusions kept.
//  - (R21) k_pw 2-row/block pipeline REGRESSED (VGPR cliff); 1 row/block.
//  - (R22) containers throttle up to 25% (profile passes may throttle even
//    when the timed run doesn't); judge by clock-independent counters.
//  - (R23) BSTR=264 pad: conflicts 7.34M -> 1.05M, k_pw 52.6 -> 49.6us.
//  - (R26) R24 reverted: k_f1 "column-owned" chased a phantom (swizzle term
//    already spread banks) and k_f2 8-way doubled k_spec's reduce chain.
//  - (R27, this round) k_pw WRITE_SIZE was 82MB vs 50MB expected: phase-1's
//    16-channel-strip scalar hb stores half-fill 64B sectors (4 waves own
//    disjoint strips of each 128B row; L2 doesn't merge) -> hb writes ~2x.
//    Fix: phase 2a (res->S F1-layout) now unconditional; new phase 3 reads
//    S back row-major and writes hb as coalesced short8 (inverse of the 2a
//    scatter).  Same barrier count for do_f1 layers; +1 barrier on last.

#define NLAYER 4

// ws offsets in floats
#define OFF_H     0L                  // hb ushorts, floats [0, 16.8M)
#define OFF_A2    16777216L           // A2 bf16: 4.2M ush = 2.1M fl
#define OFF_XFP   18874368L           // 4 x 262144 fl x-partials (A2 gap)
#define OFF_YA    33554432L           // Y fp32 (4194304 fl)
#define OFF_TAB   38010880L           // 256 fl
#define OFF_O1W   38011136L           // o1 bf16: 2048 ush = 1024 fl
#define OFF_TRIG  38013184L           // 8192 ush = 4096 fl
#define OFF_WT    38017280L           // 16384 ush = 8192 fl
#define OFF_TRIGT 38025472L           // 8192 ush = 4096 fl
#define WS_FLOATS 38029568L

// F1 B-layout c-stride in ushorts (R23: 264 = 132 words, %32 = 4 -> 4-bank
// shift per c; 256 = 4 full wraps -> 8-way conflicts)
#define BSTR 264

typedef __attribute__((ext_vector_type(8))) short short8;
typedef __attribute__((ext_vector_type(4))) float f32x4;

__device__ __forceinline__ unsigned short f2bf(float f) {
  unsigned int u = __float_as_uint(f);
  u += 0x7FFF + ((u >> 16) & 1);          // round-to-nearest-even
  return (unsigned short)(u >> 16);
}

__global__ void k_init(float* __restrict__ ws, const float* __restrict__ pw_w,
                       const float* __restrict__ o1_w) {
  float* costab = ws + OFF_TAB;
  unsigned short* o1wbf = (unsigned short*)(ws + OFF_O1W);
  unsigned short* trig = (unsigned short*)(ws + OFF_TRIG);
  unsigned short* wt = (unsigned short*)(ws + OFF_WT);
  unsigned short* trigT = (unsigned short*)(ws + OFF_TRIGT);
  int t = blockIdx.x * blockDim.x + threadIdx.x;
  int stride = gridDim.x * blockDim.x;
  for (int m = t; m < 256; m += stride)
    costab[m] = (float)cos((double)m * (3.14159265358979323846 / 128.0));
  for (int idx = t; idx < 32 * 64; idx += stride)
    o1wbf[idx] = f2bf(o1_w[idx]);               // [o][c]
  for (int idx = t; idx < 256 * 32; idx += stride) {
    int y = idx >> 5, k = idx & 31;
    int mm = ((k & 15) * y) & 255;
    double ang = (double)mm * (3.14159265358979323846 / 128.0);
    double v = (k < 16) ? cos(ang) : sin(ang);
    trig[idx] = f2bf((float)v);
  }
  for (int idx = t; idx < 32 * 256; idx += stride) {   // trigT[r][y]
    int r = idx >> 8, y = idx & 255;
    int mm = ((r & 15) * y) & 255;
    double ang = (double)mm * (3.14159265358979323846 / 128.0);
    double v = (r < 16) ? cos(ang) : sin(ang);
    trigT[idx] = f2bf((float)v);
  }
  for (int idx = t; idx < NLAYER * 64 * 64; idx += stride)
    wt[idx] = f2bf(pw_w[idx]);                  // [l][o][c]
}

// F1 + input conv (R20 fused). Block = one (b,x) row.
// Computes h[y][c] = in_b[c] + in_w[c,0]*x0 + in_w[c,1]*x1 (same expression
// as old k_in -> same f2bf inputs), writes hb (coalesced short8) AND St
// (F1 B-layout, BSTR-padded; XOR swizzle spreads lanes across banks -- R26),
// then the F1 MFMA.
__global__ void __launch_bounds__(256) k_f1(const float* __restrict__ x,
                                            const float* __restrict__ in_w,
                                            const float* __restrict__ in_b,
                                            const unsigned short* __restrict__ trigT,
                                            unsigned short* __restrict__ hb,
                                            float* __restrict__ Y) {
  __shared__ unsigned short St[64 * BSTR];
  __shared__ float X0[256], X1[256];
  int t = threadIdx.x;
  long row = blockIdx.x;
  long b = row >> 8, xr = row & 255;
  const float* xb = x + b * 131072 + (xr << 8);
  X0[t] = xb[t];
  X1[t] = xb[65536 + t];
  int c0 = (t & 7) << 3;                       // fixed 8-channel group
  float wv[16], bv[8];
  #pragma unroll
  for (int e = 0; e < 8; ++e) {
    wv[2 * e]     = in_w[(c0 + e) * 2];
    wv[2 * e + 1] = in_w[(c0 + e) * 2 + 1];
    bv[e]         = in_b[c0 + e];
  }
  __syncthreads();
  unsigned short* hrow = hb + (row << 14);
  #pragma unroll
  for (int kk = 0; kk < 8; ++kk) {
    int idx8 = t + (kk << 8);                  // (y, c-group)
    int y = idx8 >> 3;
    float x0 = X0[y], x1 = X1[y];
    int yb = y >> 3, y7 = y & 7;
    short8 v;
    #pragma unroll
    for (int e = 0; e < 8; ++e) {
      int c = c0 + e;
      unsigned short hv = f2bf(bv[e] + wv[2 * e] * x0 + wv[2 * e + 1] * x1);
      v[e] = (short)hv;
      St[c * BSTR + (((yb ^ (c >> 3)) & 31) << 3) + y7] = hv;
    }
    *(short8*)(hrow + (idx8 << 3)) = v;
  }
  __syncthreads();
  int lane = t & 63;
  int wid = t >> 6;
  int kq = lane >> 4, n = lane & 15;
  #pragma unroll
  for (int pp = 0; pp < 2; ++pp) {
    int p = wid + (pp << 2);
    int mt = p & 1, nt = p >> 1;               // mt: 0=cos/Yr, 1=sin/Yi
    int trow = (mt << 4) + n;                  // A: m = lane&15
    int c = (nt << 4) + n;                     // B: n = lane&15
    const unsigned short* abase = trigT + (trow << 8) + (kq << 3);
    f32x4 acc = {0.0f, 0.0f, 0.0f, 0.0f};
    #pragma unroll
    for (int k0 = 0; k0 < 8; ++k0) {
      short8 af = *(const short8*)(abase + (k0 << 5));
      int yb = (k0 << 2) + kq;
      short8 bf = *(const short8*)(&St[c * BSTR + (((yb ^ (c >> 3)) & 31) << 3)]);
      acc = __builtin_amdgcn_mfma_f32_16x16x32_bf16(af, bf, acc, 0, 0, 0);
    }
    float sgn = mt ? -0.0625f : 0.0625f;       // Yi = -sum sin * h / 16
    float* yp = Y + (row << 11) + (kq << 9) + (c << 1) + mt;
    #pragma unroll
    for (int r = 0; r < 4; ++r)
      yp[r << 7] = acc[r] * sgn;               // ky = kq*4 + r
  }
}

// F2 with 4-way x-split (R17): grid = (s, b, ky, cq) [2048 blocks],
// thread = (c16, kx).  Each block sums 64 x into partial s.
__global__ void __launch_bounds__(256) k_f2(const float* __restrict__ Y,
                                            const float* __restrict__ costab,
                                            float* __restrict__ Xfp) {
  __shared__ float T[256];
  int t = threadIdx.x;
  T[t] = costab[t];
  __syncthreads();
  int s = blockIdx.x >> 9;             // x-chunk [0,4)
  int blk = blockIdx.x & 511;
  int bk = blk >> 2;                   // b*16 + ky
  int b = bk >> 4, ky = bk & 15;
  int c = ((blk & 3) << 4) + (t & 15);
  int kx = t >> 4;
  int x0 = s << 6;
  const float* ybase = Y + ((long)b * 4096 + ky) * 128 + c * 2 + (long)x0 * 2048;
  float ar = 0.0f, ai = 0.0f;
  int m = (kx * x0) & 255;
  #pragma unroll 4
  for (int x = 0; x < 64; ++x) {
    float2 v = *(const float2*)(ybase + (long)x * 2048);
    float cv = T[m], sv = T[(m + 192) & 255];
    ar += v.x * cv + v.y * sv;         // (yr + i yi)(c - i s)
    ai += v.y * cv - v.x * sv;
    m = (m + kx) & 255;
  }
  float* o = Xfp + (long)s * 262144 + ((long)b * 64 + c) * 512 + (kx * 16 + ky) * 2;
  o[0] = ar * 0.0625f;
  o[1] = ai * 0.0625f;
}

// mode GEMM + I1 (R19: 512 threads; R20: xsum fused). block = b*64+o [512].
// Part A: thread (m, h): sum of 4 x-partials ((p0+p1)+(p2+p3), bit-identical
//         to old k_xsum), partial over i in [32h,32h+32) -> LDS reduce.
// Part B: thread (x, kyh): 16 kx x 8 ky FMA; A2 stores packed as 2x short8.
__global__ void __launch_bounds__(512) k_spec(const float* __restrict__ Xfp,
                                              const float* __restrict__ wr,
                                              const float* __restrict__ wi,
                                              const float* __restrict__ costab,
                                              unsigned short* __restrict__ A2) {
  __shared__ float T[256];
  __shared__ float Gr[256], Gi[256];
  __shared__ float Pr[512], Pi[512];
  int t = threadIdx.x;
  if (t < 256) T[t] = costab[t];
  int b = blockIdx.x >> 6, o = blockIdx.x & 63;
  {
    int m = t & 255, h = t >> 8;               // h in {0,1}
    float gr = 0, gi = 0;
    const float* xb = Xfp + (long)b * 32768 + m * 2 + (long)(h << 5) * 512;
    const float* wrb = wr + (long)o * 256 + m + (long)(h << 5) * 16384;
    const float* wib = wi + (long)o * 256 + m + (long)(h << 5) * 16384;
    for (int i = 0; i < 32; ++i) {
      float2 p0 = *(const float2*)(xb + (long)i * 512);
      float2 p1 = *(const float2*)(xb + 262144 + (long)i * 512);
      float2 p2 = *(const float2*)(xb + 524288 + (long)i * 512);
      float2 p3 = *(const float2*)(xb + 786432 + (long)i * 512);
      float xr = (p0.x + p1.x) + (p2.x + p3.x);
      float xi = (p0.y + p1.y) + (p2.y + p3.y);
      float wrv = wrb[(long)i * 16384], wiv = wib[(long)i * 16384];
      gr += xr * wrv - xi * wiv;
      gi += xr * wiv + xi * wrv;
    }
    Pr[t] = gr; Pi[t] = gi;
  }
  __syncthreads();
  if (t < 256) {
    Gr[t] = Pr[t] + Pr[t + 256];
    Gi[t] = Pi[t] + Pi[t + 256];
  }
  __syncthreads();
  int x = t & 255, kyh = t >> 8;               // kyh in {0,1}
  float ar[8], ai[8];
  #pragma unroll
  for (int r = 0; r < 8; ++r) { ar[r] = 0.0f; ai[r] = 0.0f; }
  for (int kx = 0; kx < 16; ++kx) {
    int mm = (kx * x) & 255;
    float cv = T[mm], sv = T[(mm + 192) & 255];
    int gb = (kx << 4) + (kyh << 3);
    #pragma unroll
    for (int r = 0; r < 8; ++r) {
      float gr = Gr[gb + r], gi = Gi[gb + r];
      ar[r] += gr * cv - gi * sv;      // (gr+i gi)(c + i s)
      ai[r] += gr * sv + gi * cv;
    }
  }
  unsigned short* ab = A2 + ((long)(b * 256 + x) << 11) + (o << 5) + (kyh << 3);
  short8 va, vb;
  #pragma unroll
  for (int r = 0; r < 8; ++r) {
    float sc = (kyh == 0 && r == 0) ? 0.00390625f : 0.0078125f;  // 1/256, 1/128
    va[r] = (short)f2bf(ar[r] * sc);
    vb[r] = (short)f2bf(-ai[r] * sc);
  }
  *(short8*)ab = va;
  *(short8*)(ab + 16) = vb;
}

// I2 + pointwise conv + GELU (in place on hb) FUSED with next layer's F1.
// Block = one full (b,x) row, 512 threads = 8 waves (proven 1-row form).
// Phase 0: stage 256x64 h tile -> S, stride 64 + XOR swizzle (c8^y)&7.
// Phase 1: wave w = (y-half w>>2, o-strip (w&3)*16); A-frags from S; gelu ->
//          8 ushort4 registers (NO global writes -- R27).
// Phase 2a (always): barrier, re-stage res into S in F1 B-layout (BSTR).
// Phase 2b (do_f1): barrier, F1 MFMA -> Y.
// Phase 3: coalesced short8 hb write-back from S (inverse of 2a scatter).
__global__ void __launch_bounds__(512) k_pw(unsigned short* __restrict__ hb,
                                            const unsigned short* __restrict__ A2,
                                            const unsigned short* __restrict__ Wt,
                                            const unsigned short* __restrict__ trig,
                                            const unsigned short* __restrict__ trigT,
                                            const float* __restrict__ pw_b,
                                            float* __restrict__ Y,
                                            int do_f1) {
  __shared__ unsigned short S[64 * BSTR];      // 33 KB; staging (16384) fits
  int t = threadIdx.x;
  long row = blockIdx.x;                       // (b,x) in [0,2048)
  int lane = t & 63;
  int wid = t >> 6;                            // 0..7
  int kq = lane >> 4, n = lane & 15;
  int half = wid >> 2;
  int o = ((wid & 3) << 4) + n;
  const unsigned short* wrow = Wt + (o << 6) + (kq << 3);
  short8 B0 = *(const short8*)(wrow);                               // c 0..31
  short8 B1 = *(const short8*)(wrow + 32);                          // c 32..63
  short8 B2 = *(const short8*)(A2 + (row << 11) + (o << 5) + (kq << 3)); // k'
  float bias = pw_b[o];
  // ---- phase 0: stage the whole row tile (256y x 64c), XOR-swizzled ----
  const unsigned short* hrow = hb + (row << 14);
  #pragma unroll
  for (int k = 0; k < 4; ++k) {
    int idx8 = t + (k << 9);                   // [0,2048) ushort8 chunks
    short8 v = *(const short8*)(hrow + (idx8 << 3));
    int yy = idx8 >> 3, c8 = idx8 & 7;
    *(short8*)(&S[(yy << 6) + (((c8 ^ yy) & 7) << 3)]) = v;
  }
  __syncthreads();                             // staging done
  // ---- phase 1: pw GEMM + gelu (results stay in regs) ----
  int s0 = (kq ^ n) & 7;                       // swizzled slot for c-group kq
  ushort4 res[8];
  #pragma unroll
  for (int i = 0; i < 8; ++i) {
    int m0 = i << 4;
    int yrow = (half << 7) + m0 + n;           // yrow&7 == n&7
    const unsigned short* srow = &S[yrow << 6];
    short8 a0 = *(const short8*)(srow + (s0 << 3));
    short8 a1 = *(const short8*)(srow + ((s0 ^ 4) << 3));
    short8 a2 = *(const short8*)(trig + (yrow << 5) + (kq << 3));
    f32x4 acc = {0.0f, 0.0f, 0.0f, 0.0f};
    acc = __builtin_amdgcn_mfma_f32_16x16x32_bf16(a0, B0, acc, 0, 0, 0);
    acc = __builtin_amdgcn_mfma_f32_16x16x32_bf16(a1, B1, acc, 0, 0, 0);
    acc = __builtin_amdgcn_mfma_f32_16x16x32_bf16(a2, B2, acc, 0, 0, 0);
    float v0 = acc[0] + bias;
    v0 = 0.5f * v0 * (1.0f + erff(v0 * 0.70710678118654752f));
    float v1 = acc[1] + bias;
    v1 = 0.5f * v1 * (1.0f + erff(v1 * 0.70710678118654752f));
    float v2 = acc[2] + bias;
    v2 = 0.5f * v2 * (1.0f + erff(v2 * 0.70710678118654752f));
    float v3 = acc[3] + bias;
    v3 = 0.5f * v3 * (1.0f + erff(v3 * 0.70710678118654752f));
    res[i].x = f2bf(v0); res[i].y = f2bf(v1);
    res[i].z = f2bf(v2); res[i].w = f2bf(v3);
  }
  __syncthreads();                             // all phase-1 S reads drained
  // ---- phase 2a: re-stage gelu tile into S in F1 B-layout (always) ----
  #pragma unroll
  for (int i = 0; i < 8; ++i) {
    int y0 = (half << 7) + (i << 4) + (kq << 2);
    int yb = y0 >> 3;
    *(ushort4*)(&S[o * BSTR + (((yb ^ (o >> 3)) & 31) << 3) + (y0 & 7)]) = res[i];
  }
  __syncthreads();
  if (do_f1) {
    // ---- phase 2b: F1 MFMA -> Y ----
    int mt = wid & 1, nt = wid >> 1;           // 8 waves = 2 mt x 4 nt
    int trow = (mt << 4) + n;
    int c = (nt << 4) + n;
    const unsigned short* abase = trigT + (trow << 8) + (kq << 3);
    f32x4 acc = {0.0f, 0.0f, 0.0f, 0.0f};
    #pragma unroll
    for (int k0 = 0; k0 < 8; ++k0) {
      short8 af = *(const short8*)(abase + (k0 << 5));
      int yb = (k0 << 2) + kq;
      short8 bf = *(const short8*)(&S[c * BSTR + (((yb ^ (c >> 3)) & 31) << 3)]);
      acc = __builtin_amdgcn_mfma_f32_16x16x32_bf16(af, bf, acc, 0, 0, 0);
    }
    float sgn = mt ? -0.0625f : 0.0625f;
    float* yp = Y + (row << 11) + (kq << 9) + (c << 1) + mt;
    #pragma unroll
    for (int r = 0; r < 4; ++r)
      yp[r << 7] = acc[r] * sgn;               // ky = kq*4 + r
  }
  // ---- phase 3: coalesced hb write-back from S (reads only; no barrier
  //      needed after 2b since both phases only read S) ----
  unsigned short* hwr = hb + (row << 14);
  #pragma unroll
  for (int j = 0; j < 4; ++j) {
    int idx8 = t + (j << 9);                   // [0,2048) chunks
    int y = idx8 >> 3, cg = (idx8 & 7) << 3;
    int yb = y >> 3, y7 = y & 7;
    short8 v;
    #pragma unroll
    for (int e = 0; e < 8; ++e) {
      int c = cg + e;
      v[e] = (short)S[c * BSTR + (((yb ^ (c >> 3)) & 31) << 3) + y7];
    }
    *(short8*)(hwr + (idx8 << 3)) = v;
  }
}

// output: hidden = H @ o1^T (bf16 MFMA, K=64), bias+gelu, then o2 dot via
// per-lane scale + butterfly shfl_xor over the quad's 16 columns.
__global__ void __launch_bounds__(256) k_out(const unsigned short* __restrict__ hb,
                                             const unsigned short* __restrict__ o1wbf,
                                             const float* __restrict__ o1_b,
                                             const float* __restrict__ o2_w,
                                             const float* __restrict__ o2_b,
                                             float* __restrict__ out) {
  __shared__ unsigned short S[128 * 88];
  int t = threadIdx.x;
  long row = blockIdx.x >> 1;                  // (b,x) in [0,2048)
  int half = blockIdx.x & 1;
  const unsigned short* hbase = hb + (row << 14) + (half << 13);
  #pragma unroll
  for (int k = 0; k < 4; ++k) {
    int idx8 = t + (k << 8);
    short8 v = *(const short8*)(hbase + (idx8 << 3));
    int yy = idx8 >> 3, c8 = idx8 & 7;
    *(short8*)(&S[yy * 88 + (c8 << 3)]) = v;
  }
  int lane = t & 63;
  int kq = lane >> 4;
  int n = lane & 15;
  int wid = t >> 6;                            // rows [32*wid, 32*wid+32)
  const unsigned short* w0 = o1wbf + (n << 6) + (kq << 3);         // o = n
  const unsigned short* w1 = o1wbf + ((n + 16) << 6) + (kq << 3);  // o = n+16
  short8 B0a = *(const short8*)(w0);
  short8 B0b = *(const short8*)(w0 + 32);
  short8 B1a = *(const short8*)(w1);
  short8 B1b = *(const short8*)(w1 + 32);
  float b0 = o1_b[n], b1 = o1_b[n + 16];
  float g0 = o2_w[n], g1 = o2_w[n + 16];
  float ob2 = o2_b[0];
  __syncthreads();
  float* outp = out + row * 256 + (half << 7);
  #pragma unroll
  for (int mt = 0; mt < 2; ++mt) {
    int m0 = (wid << 5) + (mt << 4);
    const unsigned short* srow = &S[(m0 + n) * 88 + (kq << 3)];
    short8 a0 = *(const short8*)(srow);
    short8 a1 = *(const short8*)(srow + 32);
    f32x4 c0 = {0.0f, 0.0f, 0.0f, 0.0f}, c1 = {0.0f, 0.0f, 0.0f, 0.0f};
    c0 = __builtin_amdgcn_mfma_f32_16x16x32_bf16(a0, B0a, c0, 0, 0, 0);
    c0 = __builtin_amdgcn_mfma_f32_16x16x32_bf16(a1, B0b, c0, 0, 0, 0);
    c1 = __builtin_amdgcn_mfma_f32_16x16x32_bf16(a0, B1a, c1, 0, 0, 0);
    c1 = __builtin_amdgcn_mfma_f32_16x16x32_bf16(a1, B1b, c1, 0, 0, 0);
    #pragma unroll
    for (int r = 0; r < 4; ++r) {
      float v0 = c0[r] + b0;
      v0 = 0.5f * v0 * (1.0f + erff(v0 * 0.70710678118654752f));
      float v1 = c1[r] + b1;
      v1 = 0.5f * v1 * (1.0f + erff(v1 * 0.70710678118654752f));
      float s = v0 * g0 + v1 * g1;
      s += __shfl_xor(s, 1);
      s += __shfl_xor(s, 2);
      s += __shfl_xor(s, 4);
      s += __shfl_xor(s, 8);
      if (n == 0) outp[m0 + (kq << 2) + r] = s + ob2;
    }
  }
}

extern "C" void kernel_launch(void* const* d_in, const int* in_sizes, int n_in,
                              void* d_out, int out_size, void* d_ws, size_t ws_size,
                              hipStream_t stream) {
  const float* x       = (const float*)d_in[0];
  const float* in_w    = (const float*)d_in[1];
  const float* in_b    = (const float*)d_in[2];
  const float* spec_wr = (const float*)d_in[3];
  const float* spec_wi = (const float*)d_in[4];
  const float* pw_w    = (const float*)d_in[5];
  const float* pw_b    = (const float*)d_in[6];
  const float* o1_w    = (const float*)d_in[7];
  const float* o1_b    = (const float*)d_in[8];
  const float* o2_w    = (const float*)d_in[9];
  const float* o2_b    = (const float*)d_in[10];
  float* ws = (float*)d_ws;
  unsigned short* hb = (unsigned short*)(ws + OFF_H);
  unsigned short* A2 = (unsigned short*)(ws + OFF_A2);
  float* Xfp    = ws + OFF_XFP;
  float* Y      = ws + OFF_YA;
  float* costab = ws + OFF_TAB;
  unsigned short* o1wbf = (unsigned short*)(ws + OFF_O1W);
  unsigned short* trig = (unsigned short*)(ws + OFF_TRIG);
  unsigned short* wt   = (unsigned short*)(ws + OFF_WT);
  unsigned short* trigT = (unsigned short*)(ws + OFF_TRIGT);
  float* out = (float*)d_out;

  k_init<<<73, 256, 0, stream>>>(ws, pw_w, o1_w);
  k_f1<<<2048, 256, 0, stream>>>(x, in_w, in_b, trigT, hb, Y);  // +input conv
  for (int l = 0; l < NLAYER; ++l) {
    k_f2<<<2048, 256, 0, stream>>>(Y, costab, Xfp);
    k_spec<<<512, 512, 0, stream>>>(Xfp, spec_wr + (long)l * 1048576,
                                    spec_wi + (long)l * 1048576, costab, A2);
    k_pw<<<2048, 512, 0, stream>>>(hb, A2, wt + l * 4096, trig, trigT,
                                   pw_b + l * 64, Y, (l < NLAYER - 1) ? 1 : 0);
  }
  k_out<<<4096, 256, 0, stream>>>(hb, o1wbf, o1_b, o2_w, o2_b, out);
}

// Round 14
// 463.420 us; speedup vs baseline: 1.0895x; 1.0895x over previous
//
#include <hip/hip_runtime.h>
#include <math.h>

// FNO2d: B=8, CIN=2, COUT=1, W0=64, modes 16x16, NL=4, H=W=256
// h stored channels-last BF16: [B][H][W][64] ushort.
// Y  (F1 out, fp32): [B][H(x)][16ky][64c][2]
// Xfp (F2 out, fp32): 4 x-partials of Xf [B][64c][256m][2], m = kx*16+ky
// A2 (spec out, bf16): [B*256 rows][64o][32k'] -- separate region; must not
//    overlay Y (fused k_pw writes Y while other blocks still read A2).
// Trig  (bf16): [256y][32k'] (A-frags for k_pw I2)
// TrigT (bf16): [32 rows][256y] (A-frags for F1; rows 0-15 cos, 16-31 sin)
// k_f1 (layer 0 only) = input 1x1 conv + bf16 MFMA GEMM Y = TrigT @ H.
// k_pw = bf16 MFMA GEMM [H | Trig] @ [pw_w^T ; A2] + bias -> gelu -> hb,
//        FUSED with next layer's F1 via LDS (stage -> pw -> re-stage -> F1).
// k_out = bf16 MFMA GEMM (H @ o1^T) + gelu + cross-lane o2 dot.
//
// HARD-WON RULES:
//  - (R2/R3/R5) NEVER use min-waves arg of __launch_bounds__ with per-thread
//    accumulator arrays: backend spills to hit the VGPR tier.
//  - (R4/R6/R9) per-thread accs + uniform weight streaming via s_load is
//    latency-bound; keep weights in VGPR MFMA B-frags.
//  - (R11) grid must cover 256 CUs.  (R12) fuse pairs sharing a row tile.
//  - (R13) in-place kernels must stage the ENTIRE input tile (LDS or regs)
//    behind the first in-place write -- no direct global reads after.
//  - (R16) fast A-S-erf gelu REGRESSED (TRANS-pipe rcp+exp); erff kept.
//  - (R17) thin-grid latency kernels: k_f2 4-way x-split -> +19us.
//  - (R19) k_spec widened to 512 thr -> +7us.
//  - (R20) k_in->k_f1 and k_xsum->k_spec fusions kept.
//  - (R21) k_pw 2-row/block pipeline REGRESSED (VGPR cliff); 1 row/block.
//  - (R22) containers throttle up to 25% (profile passes may throttle even
//    when the timed run doesn't); judge by clock-independent counters.
//  - (R23) BSTR=264 pad: conflicts 7.34M -> 1.05M, k_pw 52.6 -> 49.6us.
//  - (R26) R24 reverted: k_f1 "column-owned" chased a phantom (swizzle term
//    already spread banks) and k_f2 8-way doubled k_spec's reduce chain.
//  - (R28, this round) R27 reverted: "write amplification" was an
//    ARITHMETIC ERROR -- hb writes are 67.1MB (not 33.5), so 67.1+16.8 =
//    83.9MB matches the measured 82MB exactly; no amplification existed.
//    The S-bounce fix added VGPR 36->64 (res live across 2 extra barriers)
//    -> occupancy cliff, k_pw 49.6->58.4us.  Exact R12 restore (best:
//    466.1us).  k_pw structural levers are exhausted: 7 experiments, 1 win
//    (bank pad), rest null/regressed; no pipe saturated (VALU 42%, Occ 51%)
//    -- barrier-phased latency structure at its practical plateau.

#define NLAYER 4

// ws offsets in floats
#define OFF_H     0L                  // hb ushorts, floats [0, 16.8M)
#define OFF_A2    16777216L           // A2 bf16: 4.2M ush = 2.1M fl
#define OFF_XFP   18874368L           // 4 x 262144 fl x-partials (A2 gap)
#define OFF_YA    33554432L           // Y fp32 (4194304 fl)
#define OFF_TAB   38010880L           // 256 fl
#define OFF_O1W   38011136L           // o1 bf16: 2048 ush = 1024 fl
#define OFF_TRIG  38013184L           // 8192 ush = 4096 fl
#define OFF_WT    38017280L           // 16384 ush = 8192 fl
#define OFF_TRIGT 38025472L           // 8192 ush = 4096 fl
#define WS_FLOATS 38029568L

// F1 B-layout c-stride in ushorts (R23: 264 = 132 words, %32 = 4 -> 4-bank
// shift per c; 256 = 4 full wraps -> 8-way conflicts)
#define BSTR 264

typedef __attribute__((ext_vector_type(8))) short short8;
typedef __attribute__((ext_vector_type(4))) float f32x4;

__device__ __forceinline__ unsigned short f2bf(float f) {
  unsigned int u = __float_as_uint(f);
  u += 0x7FFF + ((u >> 16) & 1);          // round-to-nearest-even
  return (unsigned short)(u >> 16);
}

__global__ void k_init(float* __restrict__ ws, const float* __restrict__ pw_w,
                       const float* __restrict__ o1_w) {
  float* costab = ws + OFF_TAB;
  unsigned short* o1wbf = (unsigned short*)(ws + OFF_O1W);
  unsigned short* trig = (unsigned short*)(ws + OFF_TRIG);
  unsigned short* wt = (unsigned short*)(ws + OFF_WT);
  unsigned short* trigT = (unsigned short*)(ws + OFF_TRIGT);
  int t = blockIdx.x * blockDim.x + threadIdx.x;
  int stride = gridDim.x * blockDim.x;
  for (int m = t; m < 256; m += stride)
    costab[m] = (float)cos((double)m * (3.14159265358979323846 / 128.0));
  for (int idx = t; idx < 32 * 64; idx += stride)
    o1wbf[idx] = f2bf(o1_w[idx]);               // [o][c]
  for (int idx = t; idx < 256 * 32; idx += stride) {
    int y = idx >> 5, k = idx & 31;
    int mm = ((k & 15) * y) & 255;
    double ang = (double)mm * (3.14159265358979323846 / 128.0);
    double v = (k < 16) ? cos(ang) : sin(ang);
    trig[idx] = f2bf((float)v);
  }
  for (int idx = t; idx < 32 * 256; idx += stride) {   // trigT[r][y]
    int r = idx >> 8, y = idx & 255;
    int mm = ((r & 15) * y) & 255;
    double ang = (double)mm * (3.14159265358979323846 / 128.0);
    double v = (r < 16) ? cos(ang) : sin(ang);
    trigT[idx] = f2bf((float)v);
  }
  for (int idx = t; idx < NLAYER * 64 * 64; idx += stride)
    wt[idx] = f2bf(pw_w[idx]);                  // [l][o][c]
}

// F1 + input conv (R20 fused). Block = one (b,x) row.
// Computes h[y][c] = in_b[c] + in_w[c,0]*x0 + in_w[c,1]*x1 (same expression
// as old k_in -> same f2bf inputs), writes hb (coalesced short8) AND St
// (F1 B-layout, BSTR-padded; XOR swizzle spreads lanes across banks -- R26),
// then the F1 MFMA.
__global__ void __launch_bounds__(256) k_f1(const float* __restrict__ x,
                                            const float* __restrict__ in_w,
                                            const float* __restrict__ in_b,
                                            const unsigned short* __restrict__ trigT,
                                            unsigned short* __restrict__ hb,
                                            float* __restrict__ Y) {
  __shared__ unsigned short St[64 * BSTR];
  __shared__ float X0[256], X1[256];
  int t = threadIdx.x;
  long row = blockIdx.x;
  long b = row >> 8, xr = row & 255;
  const float* xb = x + b * 131072 + (xr << 8);
  X0[t] = xb[t];
  X1[t] = xb[65536 + t];
  int c0 = (t & 7) << 3;                       // fixed 8-channel group
  float wv[16], bv[8];
  #pragma unroll
  for (int e = 0; e < 8; ++e) {
    wv[2 * e]     = in_w[(c0 + e) * 2];
    wv[2 * e + 1] = in_w[(c0 + e) * 2 + 1];
    bv[e]         = in_b[c0 + e];
  }
  __syncthreads();
  unsigned short* hrow = hb + (row << 14);
  #pragma unroll
  for (int kk = 0; kk < 8; ++kk) {
    int idx8 = t + (kk << 8);                  // (y, c-group)
    int y = idx8 >> 3;
    float x0 = X0[y], x1 = X1[y];
    int yb = y >> 3, y7 = y & 7;
    short8 v;
    #pragma unroll
    for (int e = 0; e < 8; ++e) {
      int c = c0 + e;
      unsigned short hv = f2bf(bv[e] + wv[2 * e] * x0 + wv[2 * e + 1] * x1);
      v[e] = (short)hv;
      St[c * BSTR + (((yb ^ (c >> 3)) & 31) << 3) + y7] = hv;
    }
    *(short8*)(hrow + (idx8 << 3)) = v;
  }
  __syncthreads();
  int lane = t & 63;
  int wid = t >> 6;
  int kq = lane >> 4, n = lane & 15;
  #pragma unroll
  for (int pp = 0; pp < 2; ++pp) {
    int p = wid + (pp << 2);
    int mt = p & 1, nt = p >> 1;               // mt: 0=cos/Yr, 1=sin/Yi
    int trow = (mt << 4) + n;                  // A: m = lane&15
    int c = (nt << 4) + n;                     // B: n = lane&15
    const unsigned short* abase = trigT + (trow << 8) + (kq << 3);
    f32x4 acc = {0.0f, 0.0f, 0.0f, 0.0f};
    #pragma unroll
    for (int k0 = 0; k0 < 8; ++k0) {
      short8 af = *(const short8*)(abase + (k0 << 5));
      int yb = (k0 << 2) + kq;
      short8 bf = *(const short8*)(&St[c * BSTR + (((yb ^ (c >> 3)) & 31) << 3)]);
      acc = __builtin_amdgcn_mfma_f32_16x16x32_bf16(af, bf, acc, 0, 0, 0);
    }
    float sgn = mt ? -0.0625f : 0.0625f;       // Yi = -sum sin * h / 16
    float* yp = Y + (row << 11) + (kq << 9) + (c << 1) + mt;
    #pragma unroll
    for (int r = 0; r < 4; ++r)
      yp[r << 7] = acc[r] * sgn;               // ky = kq*4 + r
  }
}

// F2 with 4-way x-split (R17): grid = (s, b, ky, cq) [2048 blocks],
// thread = (c16, kx).  Each block sums 64 x into partial s.
__global__ void __launch_bounds__(256) k_f2(const float* __restrict__ Y,
                                            const float* __restrict__ costab,
                                            float* __restrict__ Xfp) {
  __shared__ float T[256];
  int t = threadIdx.x;
  T[t] = costab[t];
  __syncthreads();
  int s = blockIdx.x >> 9;             // x-chunk [0,4)
  int blk = blockIdx.x & 511;
  int bk = blk >> 2;                   // b*16 + ky
  int b = bk >> 4, ky = bk & 15;
  int c = ((blk & 3) << 4) + (t & 15);
  int kx = t >> 4;
  int x0 = s << 6;
  const float* ybase = Y + ((long)b * 4096 + ky) * 128 + c * 2 + (long)x0 * 2048;
  float ar = 0.0f, ai = 0.0f;
  int m = (kx * x0) & 255;
  #pragma unroll 4
  for (int x = 0; x < 64; ++x) {
    float2 v = *(const float2*)(ybase + (long)x * 2048);
    float cv = T[m], sv = T[(m + 192) & 255];
    ar += v.x * cv + v.y * sv;         // (yr + i yi)(c - i s)
    ai += v.y * cv - v.x * sv;
    m = (m + kx) & 255;
  }
  float* o = Xfp + (long)s * 262144 + ((long)b * 64 + c) * 512 + (kx * 16 + ky) * 2;
  o[0] = ar * 0.0625f;
  o[1] = ai * 0.0625f;
}

// mode GEMM + I1 (R19: 512 threads; R20: xsum fused). block = b*64+o [512].
// Part A: thread (m, h): sum of 4 x-partials ((p0+p1)+(p2+p3), bit-identical
//         to old k_xsum), partial over i in [32h,32h+32) -> LDS reduce.
// Part B: thread (x, kyh): 16 kx x 8 ky FMA; A2 stores packed as 2x short8.
__global__ void __launch_bounds__(512) k_spec(const float* __restrict__ Xfp,
                                              const float* __restrict__ wr,
                                              const float* __restrict__ wi,
                                              const float* __restrict__ costab,
                                              unsigned short* __restrict__ A2) {
  __shared__ float T[256];
  __shared__ float Gr[256], Gi[256];
  __shared__ float Pr[512], Pi[512];
  int t = threadIdx.x;
  if (t < 256) T[t] = costab[t];
  int b = blockIdx.x >> 6, o = blockIdx.x & 63;
  {
    int m = t & 255, h = t >> 8;               // h in {0,1}
    float gr = 0, gi = 0;
    const float* xb = Xfp + (long)b * 32768 + m * 2 + (long)(h << 5) * 512;
    const float* wrb = wr + (long)o * 256 + m + (long)(h << 5) * 16384;
    const float* wib = wi + (long)o * 256 + m + (long)(h << 5) * 16384;
    for (int i = 0; i < 32; ++i) {
      float2 p0 = *(const float2*)(xb + (long)i * 512);
      float2 p1 = *(const float2*)(xb + 262144 + (long)i * 512);
      float2 p2 = *(const float2*)(xb + 524288 + (long)i * 512);
      float2 p3 = *(const float2*)(xb + 786432 + (long)i * 512);
      float xr = (p0.x + p1.x) + (p2.x + p3.x);
      float xi = (p0.y + p1.y) + (p2.y + p3.y);
      float wrv = wrb[(long)i * 16384], wiv = wib[(long)i * 16384];
      gr += xr * wrv - xi * wiv;
      gi += xr * wiv + xi * wrv;
    }
    Pr[t] = gr; Pi[t] = gi;
  }
  __syncthreads();
  if (t < 256) {
    Gr[t] = Pr[t] + Pr[t + 256];
    Gi[t] = Pi[t] + Pi[t + 256];
  }
  __syncthreads();
  int x = t & 255, kyh = t >> 8;               // kyh in {0,1}
  float ar[8], ai[8];
  #pragma unroll
  for (int r = 0; r < 8; ++r) { ar[r] = 0.0f; ai[r] = 0.0f; }
  for (int kx = 0; kx < 16; ++kx) {
    int mm = (kx * x) & 255;
    float cv = T[mm], sv = T[(mm + 192) & 255];
    int gb = (kx << 4) + (kyh << 3);
    #pragma unroll
    for (int r = 0; r < 8; ++r) {
      float gr = Gr[gb + r], gi = Gi[gb + r];
      ar[r] += gr * cv - gi * sv;      // (gr+i gi)(c + i s)
      ai[r] += gr * sv + gi * cv;
    }
  }
  unsigned short* ab = A2 + ((long)(b * 256 + x) << 11) + (o << 5) + (kyh << 3);
  short8 va, vb;
  #pragma unroll
  for (int r = 0; r < 8; ++r) {
    float sc = (kyh == 0 && r == 0) ? 0.00390625f : 0.0078125f;  // 1/256, 1/128
    va[r] = (short)f2bf(ar[r] * sc);
    vb[r] = (short)f2bf(-ai[r] * sc);
  }
  *(short8*)ab = va;
  *(short8*)(ab + 16) = vb;
}

// I2 + pointwise conv + GELU (in place on hb) FUSED with next layer's F1.
// Block = one full (b,x) row, 512 threads = 8 waves (proven 1-row form).
// Phase 0: stage 256x64 h tile -> S, stride 64 + XOR swizzle (c8^y)&7.
// Phase 1: wave w = (y-half w>>2, o-strip (w&3)*16); A-frags from S; gelu ->
//          global hb + 8 ushort4 registers.
// Phase 2 (do_f1): barrier, re-stage in F1 B-layout (BSTR pad, R23),
//          barrier, F1 MFMA -> Y.
__global__ void __launch_bounds__(512) k_pw(unsigned short* __restrict__ hb,
                                            const unsigned short* __restrict__ A2,
                                            const unsigned short* __restrict__ Wt,
                                            const unsigned short* __restrict__ trig,
                                            const unsigned short* __restrict__ trigT,
                                            const float* __restrict__ pw_b,
                                            float* __restrict__ Y,
                                            int do_f1) {
  __shared__ unsigned short S[64 * BSTR];      // 33 KB; staging (16384) fits
  int t = threadIdx.x;
  long row = blockIdx.x;                       // (b,x) in [0,2048)
  int lane = t & 63;
  int wid = t >> 6;                            // 0..7
  int kq = lane >> 4, n = lane & 15;
  int half = wid >> 2;
  int o = ((wid & 3) << 4) + n;
  const unsigned short* wrow = Wt + (o << 6) + (kq << 3);
  short8 B0 = *(const short8*)(wrow);                               // c 0..31
  short8 B1 = *(const short8*)(wrow + 32);                          // c 32..63
  short8 B2 = *(const short8*)(A2 + (row << 11) + (o << 5) + (kq << 3)); // k'
  float bias = pw_b[o];
  // ---- phase 0: stage the whole row tile (256y x 64c), XOR-swizzled ----
  const unsigned short* hrow = hb + (row << 14);
  #pragma unroll
  for (int k = 0; k < 4; ++k) {
    int idx8 = t + (k << 9);                   // [0,2048) ushort8 chunks
    short8 v = *(const short8*)(hrow + (idx8 << 3));
    int yy = idx8 >> 3, c8 = idx8 & 7;
    *(short8*)(&S[(yy << 6) + (((c8 ^ yy) & 7) << 3)]) = v;
  }
  __syncthreads();                             // staging done before in-place writes
  // ---- phase 1: pw GEMM + gelu ----
  int s0 = (kq ^ n) & 7;                       // swizzled slot for c-group kq
  ushort4 res[8];
  #pragma unroll
  for (int i = 0; i < 8; ++i) {
    int m0 = i << 4;
    int yrow = (half << 7) + m0 + n;           // yrow&7 == n&7
    const unsigned short* srow = &S[yrow << 6];
    short8 a0 = *(const short8*)(srow + (s0 << 3));
    short8 a1 = *(const short8*)(srow + ((s0 ^ 4) << 3));
    short8 a2 = *(const short8*)(trig + (yrow << 5) + (kq << 3));
    f32x4 acc = {0.0f, 0.0f, 0.0f, 0.0f};
    acc = __builtin_amdgcn_mfma_f32_16x16x32_bf16(a0, B0, acc, 0, 0, 0);
    acc = __builtin_amdgcn_mfma_f32_16x16x32_bf16(a1, B1, acc, 0, 0, 0);
    acc = __builtin_amdgcn_mfma_f32_16x16x32_bf16(a2, B2, acc, 0, 0, 0);
    float v0 = acc[0] + bias;
    v0 = 0.5f * v0 * (1.0f + erff(v0 * 0.70710678118654752f));
    float v1 = acc[1] + bias;
    v1 = 0.5f * v1 * (1.0f + erff(v1 * 0.70710678118654752f));
    float v2 = acc[2] + bias;
    v2 = 0.5f * v2 * (1.0f + erff(v2 * 0.70710678118654752f));
    float v3 = acc[3] + bias;
    v3 = 0.5f * v3 * (1.0f + erff(v3 * 0.70710678118654752f));
    res[i].x = f2bf(v0); res[i].y = f2bf(v1);
    res[i].z = f2bf(v2); res[i].w = f2bf(v3);
    int y0 = (half << 7) + m0 + (kq << 2);     // rows y0..y0+3, col o
    unsigned short* ob = hb + (row << 14) + ((long)y0 << 6) + o;
    ob[0] = res[i].x; ob[64] = res[i].y; ob[128] = res[i].z; ob[192] = res[i].w;
  }
  if (do_f1) {
    __syncthreads();                           // all phase-1 S reads drained
    // ---- phase 2a: re-stage gelu tile into S in F1 B-layout (BSTR) ----
    #pragma unroll
    for (int i = 0; i < 8; ++i) {
      int y0 = (half << 7) + (i << 4) + (kq << 2);
      int yb = y0 >> 3;
      *(ushort4*)(&S[o * BSTR + (((yb ^ (o >> 3)) & 31) << 3) + (y0 & 7)]) = res[i];
    }
    __syncthreads();
    // ---- phase 2b: F1 MFMA -> Y ----
    int mt = wid & 1, nt = wid >> 1;           // 8 waves = 2 mt x 4 nt
    int trow = (mt << 4) + n;
    int c = (nt << 4) + n;
    const unsigned short* abase = trigT + (trow << 8) + (kq << 3);
    f32x4 acc = {0.0f, 0.0f, 0.0f, 0.0f};
    #pragma unroll
    for (int k0 = 0; k0 < 8; ++k0) {
      short8 af = *(const short8*)(abase + (k0 << 5));
      int yb = (k0 << 2) + kq;
      short8 bf = *(const short8*)(&S[c * BSTR + (((yb ^ (c >> 3)) & 31) << 3)]);
      acc = __builtin_amdgcn_mfma_f32_16x16x32_bf16(af, bf, acc, 0, 0, 0);
    }
    float sgn = mt ? -0.0625f : 0.0625f;
    float* yp = Y + (row << 11) + (kq << 9) + (c << 1) + mt;
    #pragma unroll
    for (int r = 0; r < 4; ++r)
      yp[r << 7] = acc[r] * sgn;               // ky = kq*4 + r
  }
}

// output: hidden = H @ o1^T (bf16 MFMA, K=64), bias+gelu, then o2 dot via
// per-lane scale + butterfly shfl_xor over the quad's 16 columns.
__global__ void __launch_bounds__(256) k_out(const unsigned short* __restrict__ hb,
                                             const unsigned short* __restrict__ o1wbf,
                                             const float* __restrict__ o1_b,
                                             const float* __restrict__ o2_w,
                                             const float* __restrict__ o2_b,
                                             float* __restrict__ out) {
  __shared__ unsigned short S[128 * 88];
  int t = threadIdx.x;
  long row = blockIdx.x >> 1;                  // (b,x) in [0,2048)
  int half = blockIdx.x & 1;
  const unsigned short* hbase = hb + (row << 14) + (half << 13);
  #pragma unroll
  for (int k = 0; k < 4; ++k) {
    int idx8 = t + (k << 8);
    short8 v = *(const short8*)(hbase + (idx8 << 3));
    int yy = idx8 >> 3, c8 = idx8 & 7;
    *(short8*)(&S[yy * 88 + (c8 << 3)]) = v;
  }
  int lane = t & 63;
  int kq = lane >> 4;
  int n = lane & 15;
  int wid = t >> 6;                            // rows [32*wid, 32*wid+32)
  const unsigned short* w0 = o1wbf + (n << 6) + (kq << 3);         // o = n
  const unsigned short* w1 = o1wbf + ((n + 16) << 6) + (kq << 3);  // o = n+16
  short8 B0a = *(const short8*)(w0);
  short8 B0b = *(const short8*)(w0 + 32);
  short8 B1a = *(const short8*)(w1);
  short8 B1b = *(const short8*)(w1 + 32);
  float b0 = o1_b[n], b1 = o1_b[n + 16];
  float g0 = o2_w[n], g1 = o2_w[n + 16];
  float ob2 = o2_b[0];
  __syncthreads();
  float* outp = out + row * 256 + (half << 7);
  #pragma unroll
  for (int mt = 0; mt < 2; ++mt) {
    int m0 = (wid << 5) + (mt << 4);
    const unsigned short* srow = &S[(m0 + n) * 88 + (kq << 3)];
    short8 a0 = *(const short8*)(srow);
    short8 a1 = *(const short8*)(srow + 32);
    f32x4 c0 = {0.0f, 0.0f, 0.0f, 0.0f}, c1 = {0.0f, 0.0f, 0.0f, 0.0f};
    c0 = __builtin_amdgcn_mfma_f32_16x16x32_bf16(a0, B0a, c0, 0, 0, 0);
    c0 = __builtin_amdgcn_mfma_f32_16x16x32_bf16(a1, B0b, c0, 0, 0, 0);
    c1 = __builtin_amdgcn_mfma_f32_16x16x32_bf16(a0, B1a, c1, 0, 0, 0);
    c1 = __builtin_amdgcn_mfma_f32_16x16x32_bf16(a1, B1b, c1, 0, 0, 0);
    #pragma unroll
    for (int r = 0; r < 4; ++r) {
      float v0 = c0[r] + b0;
      v0 = 0.5f * v0 * (1.0f + erff(v0 * 0.70710678118654752f));
      float v1 = c1[r] + b1;
      v1 = 0.5f * v1 * (1.0f + erff(v1 * 0.70710678118654752f));
      float s = v0 * g0 + v1 * g1;
      s += __shfl_xor(s, 1);
      s += __shfl_xor(s, 2);
      s += __shfl_xor(s, 4);
      s += __shfl_xor(s, 8);
      if (n == 0) outp[m0 + (kq << 2) + r] = s + ob2;
    }
  }
}

extern "C" void kernel_launch(void* const* d_in, const int* in_sizes, int n_in,
                              void* d_out, int out_size, void* d_ws, size_t ws_size,
                              hipStream_t stream) {
  const float* x       = (const float*)d_in[0];
  const float* in_w    = (const float*)d_in[1];
  const float* in_b    = (const float*)d_in[2];
  const float* spec_wr = (const float*)d_in[3];
  const float* spec_wi = (const float*)d_in[4];
  const float* pw_w    = (const float*)d_in[5];
  const float* pw_b    = (const float*)d_in[6];
  const float* o1_w    = (const float*)d_in[7];
  const float* o1_b    = (const float*)d_in[8];
  const float* o2_w    = (const float*)d_in[9];
  const float* o2_b    = (const float*)d_in[10];
  float* ws = (float*)d_ws;
  unsigned short* hb = (unsigned short*)(ws + OFF_H);
  unsigned short* A2 = (unsigned short*)(ws + OFF_A2);
  float* Xfp    = ws + OFF_XFP;
  float* Y      = ws + OFF_YA;
  float* costab = ws + OFF_TAB;
  unsigned short* o1wbf = (unsigned short*)(ws + OFF_O1W);
  unsigned short* trig = (unsigned short*)(ws + OFF_TRIG);
  unsigned short* wt   = (unsigned short*)(ws + OFF_WT);
  unsigned short* trigT = (unsigned short*)(ws + OFF_TRIGT);
  float* out = (float*)d_out;

  k_init<<<73, 256, 0, stream>>>(ws, pw_w, o1_w);
  k_f1<<<2048, 256, 0, stream>>>(x, in_w, in_b, trigT, hb, Y);  // +input conv
  for (int l = 0; l < NLAYER; ++l) {
    k_f2<<<2048, 256, 0, stream>>>(Y, costab, Xfp);
    k_spec<<<512, 512, 0, stream>>>(Xfp, spec_wr + (long)l * 1048576,
                                    spec_wi + (long)l * 1048576, costab, A2);
    k_pw<<<2048, 512, 0, stream>>>(hb, A2, wt + l * 4096, trig, trigT,
                                   pw_b + l * 64, Y, (l < NLAYER - 1) ? 1 : 0);
  }
  k_out<<<4096, 256, 0, stream>>>(hb, o1wbf, o1_b, o2_w, o2_b, out);
}

// Round 15
// 444.274 us; speedup vs baseline: 1.1365x; 1.0431x over previous
//
#include <hip/hip_runtime.h>
#include <math.h>

// FNO2d: B=8, CIN=2, COUT=1, W0=64, modes 16x16, NL=4, H=W=256
// h stored channels-last BF16: [B][H][W][64] ushort.
// Y  (F1 out, fp32): [B][H(x)][16ky][64c][2]
// Xfp (F2 out, fp32): 4 x-partials of Xf [B][64c][256m][2], m = kx*16+ky
// A2 (spec out, bf16): [B*256 rows][64o][32k'] -- separate region; must not
//    overlay Y (fused k_pw writes Y while other blocks still read A2).
// Trig  (bf16): [256y][32k'] (A-frags for k_pw I2)
// TrigT (bf16): [32 rows][256y] (A-frags for F1; rows 0-15 cos, 16-31 sin)
// k_f1 (layer 0 only) = input 1x1 conv + bf16 MFMA GEMM Y = TrigT @ H.
// k_pw = bf16 MFMA GEMM [H | Trig] @ [pw_w^T ; A2] + bias -> gelu -> hb,
//        FUSED with next layer's F1 via LDS (stage -> pw -> re-stage -> F1).
// k_out = bf16 MFMA GEMM (H @ o1^T) + gelu + cross-lane o2 dot.
//
// HARD-WON RULES:
//  - (R2/R3/R5) NEVER use min-waves arg of __launch_bounds__ with per-thread
//    accumulator arrays: backend spills to hit the VGPR tier.
//  - (R4/R6/R9) per-thread accs + uniform weight streaming via s_load is
//    latency-bound; keep weights in VGPR MFMA B-frags.
//  - (R11) grid must cover 256 CUs.  (R12) fuse pairs sharing a row tile.
//  - (R13) in-place kernels must stage the ENTIRE input tile (LDS or regs)
//    behind the first in-place write -- no direct global reads after.
//  - (R16) fast A-S-erf gelu REGRESSED (TRANS-pipe rcp+exp); erff kept.
//  - (R17) thin-grid latency kernels: k_f2 4-way x-split -> +19us.
//  - (R19) k_spec widened to 512 thr -> +7us.
//  - (R20) k_in->k_f1 and k_xsum->k_spec fusions kept.
//  - (R21) k_pw 2-row/block pipeline REGRESSED (VGPR cliff); 1 row/block.
//  - (R22) containers throttle up to 25%; judge by clock-independent
//    counters (bytes, conflict counts) across containers.
//  - (R23) BSTR=264 pad: conflicts 7.34M -> 1.05M, k_pw 52.6 -> 49.6us.
//  - (R26) R24 reverted: k_f1 "column-owned" chased a phantom; k_f2 8-way
//    doubled k_spec's reduce chain.
//  - (R28) R27 reverted: "write amplification" was an arithmetic error
//    (hb = 67.1MB, expected total 83.9 ~= measured 82).  R12 config is the
//    stable base: 463.4/466.1/468.9us across three containers.
//  - (R29, this round) k_f2's ybase is kx-INDEPENDENT: all 16 kx-threads
//    loaded the same 64 float2s (16x redundant strided loads, 4-deep
//    pipeline).  Coop-stage the 64x(16c) slice to LDS once (8KB, 4
//    loads/thread, conflict-free both sides), FMA loop reads LDS.
//    Bit-identical accumulation.

#define NLAYER 4

// ws offsets in floats
#define OFF_H     0L                  // hb ushorts, floats [0, 16.8M)
#define OFF_A2    16777216L           // A2 bf16: 4.2M ush = 2.1M fl
#define OFF_XFP   18874368L           // 4 x 262144 fl x-partials (A2 gap)
#define OFF_YA    33554432L           // Y fp32 (4194304 fl)
#define OFF_TAB   38010880L           // 256 fl
#define OFF_O1W   38011136L           // o1 bf16: 2048 ush = 1024 fl
#define OFF_TRIG  38013184L           // 8192 ush = 4096 fl
#define OFF_WT    38017280L           // 16384 ush = 8192 fl
#define OFF_TRIGT 38025472L           // 8192 ush = 4096 fl
#define WS_FLOATS 38029568L

// F1 B-layout c-stride in ushorts (R23: 264 = 132 words, %32 = 4 -> 4-bank
// shift per c; 256 = 4 full wraps -> 8-way conflicts)
#define BSTR 264

typedef __attribute__((ext_vector_type(8))) short short8;
typedef __attribute__((ext_vector_type(4))) float f32x4;

__device__ __forceinline__ unsigned short f2bf(float f) {
  unsigned int u = __float_as_uint(f);
  u += 0x7FFF + ((u >> 16) & 1);          // round-to-nearest-even
  return (unsigned short)(u >> 16);
}

__global__ void k_init(float* __restrict__ ws, const float* __restrict__ pw_w,
                       const float* __restrict__ o1_w) {
  float* costab = ws + OFF_TAB;
  unsigned short* o1wbf = (unsigned short*)(ws + OFF_O1W);
  unsigned short* trig = (unsigned short*)(ws + OFF_TRIG);
  unsigned short* wt = (unsigned short*)(ws + OFF_WT);
  unsigned short* trigT = (unsigned short*)(ws + OFF_TRIGT);
  int t = blockIdx.x * blockDim.x + threadIdx.x;
  int stride = gridDim.x * blockDim.x;
  for (int m = t; m < 256; m += stride)
    costab[m] = (float)cos((double)m * (3.14159265358979323846 / 128.0));
  for (int idx = t; idx < 32 * 64; idx += stride)
    o1wbf[idx] = f2bf(o1_w[idx]);               // [o][c]
  for (int idx = t; idx < 256 * 32; idx += stride) {
    int y = idx >> 5, k = idx & 31;
    int mm = ((k & 15) * y) & 255;
    double ang = (double)mm * (3.14159265358979323846 / 128.0);
    double v = (k < 16) ? cos(ang) : sin(ang);
    trig[idx] = f2bf((float)v);
  }
  for (int idx = t; idx < 32 * 256; idx += stride) {   // trigT[r][y]
    int r = idx >> 8, y = idx & 255;
    int mm = ((r & 15) * y) & 255;
    double ang = (double)mm * (3.14159265358979323846 / 128.0);
    double v = (r < 16) ? cos(ang) : sin(ang);
    trigT[idx] = f2bf((float)v);
  }
  for (int idx = t; idx < NLAYER * 64 * 64; idx += stride)
    wt[idx] = f2bf(pw_w[idx]);                  // [l][o][c]
}

// F1 + input conv (R20 fused). Block = one (b,x) row.
// Computes h[y][c] = in_b[c] + in_w[c,0]*x0 + in_w[c,1]*x1 (same expression
// as old k_in -> same f2bf inputs), writes hb (coalesced short8) AND St
// (F1 B-layout, BSTR-padded; XOR swizzle spreads lanes across banks -- R26),
// then the F1 MFMA.
__global__ void __launch_bounds__(256) k_f1(const float* __restrict__ x,
                                            const float* __restrict__ in_w,
                                            const float* __restrict__ in_b,
                                            const unsigned short* __restrict__ trigT,
                                            unsigned short* __restrict__ hb,
                                            float* __restrict__ Y) {
  __shared__ unsigned short St[64 * BSTR];
  __shared__ float X0[256], X1[256];
  int t = threadIdx.x;
  long row = blockIdx.x;
  long b = row >> 8, xr = row & 255;
  const float* xb = x + b * 131072 + (xr << 8);
  X0[t] = xb[t];
  X1[t] = xb[65536 + t];
  int c0 = (t & 7) << 3;                       // fixed 8-channel group
  float wv[16], bv[8];
  #pragma unroll
  for (int e = 0; e < 8; ++e) {
    wv[2 * e]     = in_w[(c0 + e) * 2];
    wv[2 * e + 1] = in_w[(c0 + e) * 2 + 1];
    bv[e]         = in_b[c0 + e];
  }
  __syncthreads();
  unsigned short* hrow = hb + (row << 14);
  #pragma unroll
  for (int kk = 0; kk < 8; ++kk) {
    int idx8 = t + (kk << 8);                  // (y, c-group)
    int y = idx8 >> 3;
    float x0 = X0[y], x1 = X1[y];
    int yb = y >> 3, y7 = y & 7;
    short8 v;
    #pragma unroll
    for (int e = 0; e < 8; ++e) {
      int c = c0 + e;
      unsigned short hv = f2bf(bv[e] + wv[2 * e] * x0 + wv[2 * e + 1] * x1);
      v[e] = (short)hv;
      St[c * BSTR + (((yb ^ (c >> 3)) & 31) << 3) + y7] = hv;
    }
    *(short8*)(hrow + (idx8 << 3)) = v;
  }
  __syncthreads();
  int lane = t & 63;
  int wid = t >> 6;
  int kq = lane >> 4, n = lane & 15;
  #pragma unroll
  for (int pp = 0; pp < 2; ++pp) {
    int p = wid + (pp << 2);
    int mt = p & 1, nt = p >> 1;               // mt: 0=cos/Yr, 1=sin/Yi
    int trow = (mt << 4) + n;                  // A: m = lane&15
    int c = (nt << 4) + n;                     // B: n = lane&15
    const unsigned short* abase = trigT + (trow << 8) + (kq << 3);
    f32x4 acc = {0.0f, 0.0f, 0.0f, 0.0f};
    #pragma unroll
    for (int k0 = 0; k0 < 8; ++k0) {
      short8 af = *(const short8*)(abase + (k0 << 5));
      int yb = (k0 << 2) + kq;
      short8 bf = *(const short8*)(&St[c * BSTR + (((yb ^ (c >> 3)) & 31) << 3)]);
      acc = __builtin_amdgcn_mfma_f32_16x16x32_bf16(af, bf, acc, 0, 0, 0);
    }
    float sgn = mt ? -0.0625f : 0.0625f;       // Yi = -sum sin * h / 16
    float* yp = Y + (row << 11) + (kq << 9) + (c << 1) + mt;
    #pragma unroll
    for (int r = 0; r < 4; ++r)
      yp[r << 7] = acc[r] * sgn;               // ky = kq*4 + r
  }
}

// F2 with 4-way x-split (R17) + coop LDS staging (R29):
// grid = (s, b, ky, cq) [2048 blocks], thread = (c16, kx).
// Phase A: stage Y[b][x0..x0+64)[ky][16c][2] -> YS (8KB) once per block
//          (old code: each of the 16 kx-threads loaded the same 64 float2s).
// Phase B: FMA loop reads YS[x][c16] (x loop-uniform -> broadcast,
//          conflict-free).  Bit-identical accumulation.
__global__ void __launch_bounds__(256) k_f2(const float* __restrict__ Y,
                                            const float* __restrict__ costab,
                                            float* __restrict__ Xfp) {
  __shared__ float T[256];
  __shared__ float2 YS[64][16];
  int t = threadIdx.x;
  T[t] = costab[t];
  int s = blockIdx.x >> 9;             // x-chunk [0,4)
  int blk = blockIdx.x & 511;
  int bk = blk >> 2;                   // b*16 + ky
  int b = bk >> 4, ky = bk & 15;
  int cq = blk & 3;
  int x0 = s << 6;
  // phase A: coop stage.  Per x-row: 32 consecutive floats (16 float2).
  const float* yb2 = Y + ((long)(b * 256 + x0)) * 2048 + ky * 128 + (cq << 5);
  #pragma unroll
  for (int k = 0; k < 4; ++k) {
    int idx = t + (k << 8);            // [0,1024) float2 slots
    int xx = idx >> 4, f2i = idx & 15;
    YS[xx][f2i] = *(const float2*)(yb2 + (long)xx * 2048 + (f2i << 1));
  }
  __syncthreads();
  // phase B: per-thread FMA from LDS.
  int c16 = t & 15;
  int c = (cq << 4) + c16;
  int kx = t >> 4;
  float ar = 0.0f, ai = 0.0f;
  int m = (kx * x0) & 255;
  #pragma unroll 4
  for (int x = 0; x < 64; ++x) {
    float2 v = YS[x][c16];
    float cv = T[m], sv = T[(m + 192) & 255];
    ar += v.x * cv + v.y * sv;         // (yr + i yi)(c - i s)
    ai += v.y * cv - v.x * sv;
    m = (m + kx) & 255;
  }
  float* o = Xfp + (long)s * 262144 + ((long)b * 64 + c) * 512 + (kx * 16 + ky) * 2;
  o[0] = ar * 0.0625f;
  o[1] = ai * 0.0625f;
}

// mode GEMM + I1 (R19: 512 threads; R20: xsum fused). block = b*64+o [512].
// Part A: thread (m, h): sum of 4 x-partials ((p0+p1)+(p2+p3), bit-identical
//         to old k_xsum), partial over i in [32h,32h+32) -> LDS reduce.
// Part B: thread (x, kyh): 16 kx x 8 ky FMA; A2 stores packed as 2x short8.
__global__ void __launch_bounds__(512) k_spec(const float* __restrict__ Xfp,
                                              const float* __restrict__ wr,
                                              const float* __restrict__ wi,
                                              const float* __restrict__ costab,
                                              unsigned short* __restrict__ A2) {
  __shared__ float T[256];
  __shared__ float Gr[256], Gi[256];
  __shared__ float Pr[512], Pi[512];
  int t = threadIdx.x;
  if (t < 256) T[t] = costab[t];
  int b = blockIdx.x >> 6, o = blockIdx.x & 63;
  {
    int m = t & 255, h = t >> 8;               // h in {0,1}
    float gr = 0, gi = 0;
    const float* xb = Xfp + (long)b * 32768 + m * 2 + (long)(h << 5) * 512;
    const float* wrb = wr + (long)o * 256 + m + (long)(h << 5) * 16384;
    const float* wib = wi + (long)o * 256 + m + (long)(h << 5) * 16384;
    for (int i = 0; i < 32; ++i) {
      float2 p0 = *(const float2*)(xb + (long)i * 512);
      float2 p1 = *(const float2*)(xb + 262144 + (long)i * 512);
      float2 p2 = *(const float2*)(xb + 524288 + (long)i * 512);
      float2 p3 = *(const float2*)(xb + 786432 + (long)i * 512);
      float xr = (p0.x + p1.x) + (p2.x + p3.x);
      float xi = (p0.y + p1.y) + (p2.y + p3.y);
      float wrv = wrb[(long)i * 16384], wiv = wib[(long)i * 16384];
      gr += xr * wrv - xi * wiv;
      gi += xr * wiv + xi * wrv;
    }
    Pr[t] = gr; Pi[t] = gi;
  }
  __syncthreads();
  if (t < 256) {
    Gr[t] = Pr[t] + Pr[t + 256];
    Gi[t] = Pi[t] + Pi[t + 256];
  }
  __syncthreads();
  int x = t & 255, kyh = t >> 8;               // kyh in {0,1}
  float ar[8], ai[8];
  #pragma unroll
  for (int r = 0; r < 8; ++r) { ar[r] = 0.0f; ai[r] = 0.0f; }
  for (int kx = 0; kx < 16; ++kx) {
    int mm = (kx * x) & 255;
    float cv = T[mm], sv = T[(mm + 192) & 255];
    int gb = (kx << 4) + (kyh << 3);
    #pragma unroll
    for (int r = 0; r < 8; ++r) {
      float gr = Gr[gb + r], gi = Gi[gb + r];
      ar[r] += gr * cv - gi * sv;      // (gr+i gi)(c + i s)
      ai[r] += gr * sv + gi * cv;
    }
  }
  unsigned short* ab = A2 + ((long)(b * 256 + x) << 11) + (o << 5) + (kyh << 3);
  short8 va, vb;
  #pragma unroll
  for (int r = 0; r < 8; ++r) {
    float sc = (kyh == 0 && r == 0) ? 0.00390625f : 0.0078125f;  // 1/256, 1/128
    va[r] = (short)f2bf(ar[r] * sc);
    vb[r] = (short)f2bf(-ai[r] * sc);
  }
  *(short8*)ab = va;
  *(short8*)(ab + 16) = vb;
}

// I2 + pointwise conv + GELU (in place on hb) FUSED with next layer's F1.
// Block = one full (b,x) row, 512 threads = 8 waves (proven 1-row form).
// Phase 0: stage 256x64 h tile -> S, stride 64 + XOR swizzle (c8^y)&7.
// Phase 1: wave w = (y-half w>>2, o-strip (w&3)*16); A-frags from S; gelu ->
//          global hb + 8 ushort4 registers.
// Phase 2 (do_f1): barrier, re-stage in F1 B-layout (BSTR pad, R23),
//          barrier, F1 MFMA -> Y.
__global__ void __launch_bounds__(512) k_pw(unsigned short* __restrict__ hb,
                                            const unsigned short* __restrict__ A2,
                                            const unsigned short* __restrict__ Wt,
                                            const unsigned short* __restrict__ trig,
                                            const unsigned short* __restrict__ trigT,
                                            const float* __restrict__ pw_b,
                                            float* __restrict__ Y,
                                            int do_f1) {
  __shared__ unsigned short S[64 * BSTR];      // 33 KB; staging (16384) fits
  int t = threadIdx.x;
  long row = blockIdx.x;                       // (b,x) in [0,2048)
  int lane = t & 63;
  int wid = t >> 6;                            // 0..7
  int kq = lane >> 4, n = lane & 15;
  int half = wid >> 2;
  int o = ((wid & 3) << 4) + n;
  const unsigned short* wrow = Wt + (o << 6) + (kq << 3);
  short8 B0 = *(const short8*)(wrow);                               // c 0..31
  short8 B1 = *(const short8*)(wrow + 32);                          // c 32..63
  short8 B2 = *(const short8*)(A2 + (row << 11) + (o << 5) + (kq << 3)); // k'
  float bias = pw_b[o];
  // ---- phase 0: stage the whole row tile (256y x 64c), XOR-swizzled ----
  const unsigned short* hrow = hb + (row << 14);
  #pragma unroll
  for (int k = 0; k < 4; ++k) {
    int idx8 = t + (k << 9);                   // [0,2048) ushort8 chunks
    short8 v = *(const short8*)(hrow + (idx8 << 3));
    int yy = idx8 >> 3, c8 = idx8 & 7;
    *(short8*)(&S[(yy << 6) + (((c8 ^ yy) & 7) << 3)]) = v;
  }
  __syncthreads();                             // staging done before in-place writes
  // ---- phase 1: pw GEMM + gelu ----
  int s0 = (kq ^ n) & 7;                       // swizzled slot for c-group kq
  ushort4 res[8];
  #pragma unroll
  for (int i = 0; i < 8; ++i) {
    int m0 = i << 4;
    int yrow = (half << 7) + m0 + n;           // yrow&7 == n&7
    const unsigned short* srow = &S[yrow << 6];
    short8 a0 = *(const short8*)(srow + (s0 << 3));
    short8 a1 = *(const short8*)(srow + ((s0 ^ 4) << 3));
    short8 a2 = *(const short8*)(trig + (yrow << 5) + (kq << 3));
    f32x4 acc = {0.0f, 0.0f, 0.0f, 0.0f};
    acc = __builtin_amdgcn_mfma_f32_16x16x32_bf16(a0, B0, acc, 0, 0, 0);
    acc = __builtin_amdgcn_mfma_f32_16x16x32_bf16(a1, B1, acc, 0, 0, 0);
    acc = __builtin_amdgcn_mfma_f32_16x16x32_bf16(a2, B2, acc, 0, 0, 0);
    float v0 = acc[0] + bias;
    v0 = 0.5f * v0 * (1.0f + erff(v0 * 0.70710678118654752f));
    float v1 = acc[1] + bias;
    v1 = 0.5f * v1 * (1.0f + erff(v1 * 0.70710678118654752f));
    float v2 = acc[2] + bias;
    v2 = 0.5f * v2 * (1.0f + erff(v2 * 0.70710678118654752f));
    float v3 = acc[3] + bias;
    v3 = 0.5f * v3 * (1.0f + erff(v3 * 0.70710678118654752f));
    res[i].x = f2bf(v0); res[i].y = f2bf(v1);
    res[i].z = f2bf(v2); res[i].w = f2bf(v3);
    int y0 = (half << 7) + m0 + (kq << 2);     // rows y0..y0+3, col o
    unsigned short* ob = hb + (row << 14) + ((long)y0 << 6) + o;
    ob[0] = res[i].x; ob[64] = res[i].y; ob[128] = res[i].z; ob[192] = res[i].w;
  }
  if (do_f1) {
    __syncthreads();                           // all phase-1 S reads drained
    // ---- phase 2a: re-stage gelu tile into S in F1 B-layout (BSTR) ----
    #pragma unroll
    for (int i = 0; i < 8; ++i) {
      int y0 = (half << 7) + (i << 4) + (kq << 2);
      int yb = y0 >> 3;
      *(ushort4*)(&S[o * BSTR + (((yb ^ (o >> 3)) & 31) << 3) + (y0 & 7)]) = res[i];
    }
    __syncthreads();
    // ---- phase 2b: F1 MFMA -> Y ----
    int mt = wid & 1, nt = wid >> 1;           // 8 waves = 2 mt x 4 nt
    int trow = (mt << 4) + n;
    int c = (nt << 4) + n;
    const unsigned short* abase = trigT + (trow << 8) + (kq << 3);
    f32x4 acc = {0.0f, 0.0f, 0.0f, 0.0f};
    #pragma unroll
    for (int k0 = 0; k0 < 8; ++k0) {
      short8 af = *(const short8*)(abase + (k0 << 5));
      int yb = (k0 << 2) + kq;
      short8 bf = *(const short8*)(&S[c * BSTR + (((yb ^ (c >> 3)) & 31) << 3)]);
      acc = __builtin_amdgcn_mfma_f32_16x16x32_bf16(af, bf, acc, 0, 0, 0);
    }
    float sgn = mt ? -0.0625f : 0.0625f;
    float* yp = Y + (row << 11) + (kq << 9) + (c << 1) + mt;
    #pragma unroll
    for (int r = 0; r < 4; ++r)
      yp[r << 7] = acc[r] * sgn;               // ky = kq*4 + r
  }
}

// output: hidden = H @ o1^T (bf16 MFMA, K=64), bias+gelu, then o2 dot via
// per-lane scale + butterfly shfl_xor over the quad's 16 columns.
__global__ void __launch_bounds__(256) k_out(const unsigned short* __restrict__ hb,
                                             const unsigned short* __restrict__ o1wbf,
                                             const float* __restrict__ o1_b,
                                             const float* __restrict__ o2_w,
                                             const float* __restrict__ o2_b,
                                             float* __restrict__ out) {
  __shared__ unsigned short S[128 * 88];
  int t = threadIdx.x;
  long row = blockIdx.x >> 1;                  // (b,x) in [0,2048)
  int half = blockIdx.x & 1;
  const unsigned short* hbase = hb + (row << 14) + (half << 13);
  #pragma unroll
  for (int k = 0; k < 4; ++k) {
    int idx8 = t + (k << 8);
    short8 v = *(const short8*)(hbase + (idx8 << 3));
    int yy = idx8 >> 3, c8 = idx8 & 7;
    *(short8*)(&S[yy * 88 + (c8 << 3)]) = v;
  }
  int lane = t & 63;
  int kq = lane >> 4;
  int n = lane & 15;
  int wid = t >> 6;                            // rows [32*wid, 32*wid+32)
  const unsigned short* w0 = o1wbf + (n << 6) + (kq << 3);         // o = n
  const unsigned short* w1 = o1wbf + ((n + 16) << 6) + (kq << 3);  // o = n+16
  short8 B0a = *(const short8*)(w0);
  short8 B0b = *(const short8*)(w0 + 32);
  short8 B1a = *(const short8*)(w1);
  short8 B1b = *(const short8*)(w1 + 32);
  float b0 = o1_b[n], b1 = o1_b[n + 16];
  float g0 = o2_w[n], g1 = o2_w[n + 16];
  float ob2 = o2_b[0];
  __syncthreads();
  float* outp = out + row * 256 + (half << 7);
  #pragma unroll
  for (int mt = 0; mt < 2; ++mt) {
    int m0 = (wid << 5) + (mt << 4);
    const unsigned short* srow = &S[(m0 + n) * 88 + (kq << 3)];
    short8 a0 = *(const short8*)(srow);
    short8 a1 = *(const short8*)(srow + 32);
    f32x4 c0 = {0.0f, 0.0f, 0.0f, 0.0f}, c1 = {0.0f, 0.0f, 0.0f, 0.0f};
    c0 = __builtin_amdgcn_mfma_f32_16x16x32_bf16(a0, B0a, c0, 0, 0, 0);
    c0 = __builtin_amdgcn_mfma_f32_16x16x32_bf16(a1, B0b, c0, 0, 0, 0);
    c1 = __builtin_amdgcn_mfma_f32_16x16x32_bf16(a0, B1a, c1, 0, 0, 0);
    c1 = __builtin_amdgcn_mfma_f32_16x16x32_bf16(a1, B1b, c1, 0, 0, 0);
    #pragma unroll
    for (int r = 0; r < 4; ++r) {
      float v0 = c0[r] + b0;
      v0 = 0.5f * v0 * (1.0f + erff(v0 * 0.70710678118654752f));
      float v1 = c1[r] + b1;
      v1 = 0.5f * v1 * (1.0f + erff(v1 * 0.70710678118654752f));
      float s = v0 * g0 + v1 * g1;
      s += __shfl_xor(s, 1);
      s += __shfl_xor(s, 2);
      s += __shfl_xor(s, 4);
      s += __shfl_xor(s, 8);
      if (n == 0) outp[m0 + (kq << 2) + r] = s + ob2;
    }
  }
}

extern "C" void kernel_launch(void* const* d_in, const int* in_sizes, int n_in,
                              void* d_out, int out_size, void* d_ws, size_t ws_size,
                              hipStream_t stream) {
  const float* x       = (const float*)d_in[0];
  const float* in_w    = (const float*)d_in[1];
  const float* in_b    = (const float*)d_in[2];
  const float* spec_wr = (const float*)d_in[3];
  const float* spec_wi = (const float*)d_in[4];
  const float* pw_w    = (const float*)d_in[5];
  const float* pw_b    = (const float*)d_in[6];
  const float* o1_w    = (const float*)d_in[7];
  const float* o1_b    = (const float*)d_in[8];
  const float* o2_w    = (const float*)d_in[9];
  const float* o2_b    = (const float*)d_in[10];
  float* ws = (float*)d_ws;
  unsigned short* hb = (unsigned short*)(ws + OFF_H);
  unsigned short* A2 = (unsigned short*)(ws + OFF_A2);
  float* Xfp    = ws + OFF_XFP;
  float* Y      = ws + OFF_YA;
  float* costab = ws + OFF_TAB;
  unsigned short* o1wbf = (unsigned short*)(ws + OFF_O1W);
  unsigned short* trig = (unsigned short*)(ws + OFF_TRIG);
  unsigned short* wt   = (unsigned short*)(ws + OFF_WT);
  unsigned short* trigT = (unsigned short*)(ws + OFF_TRIGT);
  float* out = (float*)d_out;

  k_init<<<73, 256, 0, stream>>>(ws, pw_w, o1_w);
  k_f1<<<2048, 256, 0, stream>>>(x, in_w, in_b, trigT, hb, Y);  // +input conv
  for (int l = 0; l < NLAYER; ++l) {
    k_f2<<<2048, 256, 0, stream>>>(Y, costab, Xfp);
    k_spec<<<512, 512, 0, stream>>>(Xfp, spec_wr + (long)l * 1048576,
                                    spec_wi + (long)l * 1048576, costab, A2);
    k_pw<<<2048, 512, 0, stream>>>(hb, A2, wt + l * 4096, trig, trigT,
                                   pw_b + l * 64, Y, (l < NLAYER - 1) ? 1 : 0);
  }
  k_out<<<4096, 256, 0, stream>>>(hb, o1wbf, o1_b, o2_w, o2_b, out);
}

// Round 16
// 405.323 us; speedup vs baseline: 1.2457x; 1.0961x over previous
//
#include <hip/hip_runtime.h>
#include <math.h>

// FNO2d: B=8, CIN=2, COUT=1, W0=64, modes 16x16, NL=4, H=W=256
// h stored channels-last BF16: [B][H][W][64] ushort.
// Y  (F1 out, fp32): [B][H(x)][16ky][64c][2]
// Xfp (F2 out, fp32): 4 x-partials of Xf; Xf (fp32): [B][64c][256m][2]
// A2 (spec out, bf16): [B*256 rows][64o][32k']
// Trig  (bf16): [256y][32k'] (A-frags for k_pw I2)
// TrigT (bf16): [32 rows][256y] (A-frags for F1; rows 0-15 cos, 16-31 sin)
// k_f1 (layer 0 only) = input 1x1 conv + bf16 MFMA GEMM Y = TrigT @ H.
// k_pw = bf16 MFMA GEMM [H | Trig] @ [pw_w^T ; A2] + bias -> gelu -> hb,
//        FUSED with next layer's F1 via LDS (stage -> pw -> re-stage -> F1).
// k_out = bf16 MFMA GEMM (H @ o1^T) + gelu + cross-lane o2 dot.
//
// HARD-WON RULES:
//  - (R2/R3/R5) NEVER use min-waves arg of __launch_bounds__ with per-thread
//    accumulator arrays: backend spills to hit the VGPR tier.
//  - (R4/R6/R9) per-thread accs + uniform weight streaming via s_load is
//    latency-bound; keep weights in VGPR MFMA B-frags.
//  - (R11) grid must cover 256 CUs.  (R12) fuse pairs sharing a row tile.
//  - (R13) in-place kernels must stage the ENTIRE input tile (LDS or regs)
//    behind the first in-place write -- no direct global reads after.
//  - (R16) fast A-S-erf gelu REGRESSED (TRANS-pipe rcp+exp); erff kept.
//  - (R17) thin-grid latency kernels: k_f2 4-way x-split -> +19us.
//  - (R19) k_spec widened to 512 thr -> +7us.
//  - (R20) k_in->k_f1 fusion kept.
//  - (R21) k_pw 2-row/block pipeline REGRESSED (VGPR cliff); 1 row/block.
//  - (R22) containers throttle up to 25%; judge by clock-independent
//    counters (bytes, conflict counts) across containers.
//  - (R23) BSTR=264 pad: conflicts 7.34M -> 1.05M, k_pw 52.6 -> 49.6us.
//  - (R26) k_f2 8-way split doubled k_spec's reduce chain: REGRESSED.
//    k_spec's serial load chain is the sensitive path.
//  - (R28) R27 "write amplification" was an arithmetic error; R12 base.
//  - (R29) k_f2 coop LDS staging (kx-independent loads were 16x redundant):
//    463->444us.  Wins come from address-math audits, not speculation.
//  - (R30, this round) k_spec's 4-partial sum is o-INDEPENDENT: all 64
//    o-blocks of a b redid it (4 extra loads in the 6-load/iter serial
//    chain, 64x redundant).  Re-split k_xsum (proven R19 kernel, same
//    (p0+p1)+(p2+p3) association); k_spec part A now 3 loads/iter.

#define NLAYER 4

// ws offsets in floats
#define OFF_H     0L                  // hb ushorts, floats [0, 16.8M)
#define OFF_A2    16777216L           // A2 bf16: 4.2M ush = 2.1M fl
#define OFF_XFP   18874368L           // 4 x 262144 fl x-partials (A2 gap)
#define OFF_YA    33554432L           // Y fp32 (4194304 fl)
#define OFF_XF    37748736L           // 262144 fl (reduced Xf)
#define OFF_TAB   38010880L           // 256 fl
#define OFF_O1W   38011136L           // o1 bf16: 2048 ush = 1024 fl
#define OFF_TRIG  38013184L           // 8192 ush = 4096 fl
#define OFF_WT    38017280L           // 16384 ush = 8192 fl
#define OFF_TRIGT 38025472L           // 8192 ush = 4096 fl
#define WS_FLOATS 38029568L

// F1 B-layout c-stride in ushorts (R23: 264 = 132 words, %32 = 4 -> 4-bank
// shift per c; 256 = 4 full wraps -> 8-way conflicts)
#define BSTR 264

typedef __attribute__((ext_vector_type(8))) short short8;
typedef __attribute__((ext_vector_type(4))) float f32x4;

__device__ __forceinline__ unsigned short f2bf(float f) {
  unsigned int u = __float_as_uint(f);
  u += 0x7FFF + ((u >> 16) & 1);          // round-to-nearest-even
  return (unsigned short)(u >> 16);
}

__global__ void k_init(float* __restrict__ ws, const float* __restrict__ pw_w,
                       const float* __restrict__ o1_w) {
  float* costab = ws + OFF_TAB;
  unsigned short* o1wbf = (unsigned short*)(ws + OFF_O1W);
  unsigned short* trig = (unsigned short*)(ws + OFF_TRIG);
  unsigned short* wt = (unsigned short*)(ws + OFF_WT);
  unsigned short* trigT = (unsigned short*)(ws + OFF_TRIGT);
  int t = blockIdx.x * blockDim.x + threadIdx.x;
  int stride = gridDim.x * blockDim.x;
  for (int m = t; m < 256; m += stride)
    costab[m] = (float)cos((double)m * (3.14159265358979323846 / 128.0));
  for (int idx = t; idx < 32 * 64; idx += stride)
    o1wbf[idx] = f2bf(o1_w[idx]);               // [o][c]
  for (int idx = t; idx < 256 * 32; idx += stride) {
    int y = idx >> 5, k = idx & 31;
    int mm = ((k & 15) * y) & 255;
    double ang = (double)mm * (3.14159265358979323846 / 128.0);
    double v = (k < 16) ? cos(ang) : sin(ang);
    trig[idx] = f2bf((float)v);
  }
  for (int idx = t; idx < 32 * 256; idx += stride) {   // trigT[r][y]
    int r = idx >> 8, y = idx & 255;
    int mm = ((r & 15) * y) & 255;
    double ang = (double)mm * (3.14159265358979323846 / 128.0);
    double v = (r < 16) ? cos(ang) : sin(ang);
    trigT[idx] = f2bf((float)v);
  }
  for (int idx = t; idx < NLAYER * 64 * 64; idx += stride)
    wt[idx] = f2bf(pw_w[idx]);                  // [l][o][c]
}

// F1 + input conv (R20 fused). Block = one (b,x) row.
__global__ void __launch_bounds__(256) k_f1(const float* __restrict__ x,
                                            const float* __restrict__ in_w,
                                            const float* __restrict__ in_b,
                                            const unsigned short* __restrict__ trigT,
                                            unsigned short* __restrict__ hb,
                                            float* __restrict__ Y) {
  __shared__ unsigned short St[64 * BSTR];
  __shared__ float X0[256], X1[256];
  int t = threadIdx.x;
  long row = blockIdx.x;
  long b = row >> 8, xr = row & 255;
  const float* xb = x + b * 131072 + (xr << 8);
  X0[t] = xb[t];
  X1[t] = xb[65536 + t];
  int c0 = (t & 7) << 3;                       // fixed 8-channel group
  float wv[16], bv[8];
  #pragma unroll
  for (int e = 0; e < 8; ++e) {
    wv[2 * e]     = in_w[(c0 + e) * 2];
    wv[2 * e + 1] = in_w[(c0 + e) * 2 + 1];
    bv[e]         = in_b[c0 + e];
  }
  __syncthreads();
  unsigned short* hrow = hb + (row << 14);
  #pragma unroll
  for (int kk = 0; kk < 8; ++kk) {
    int idx8 = t + (kk << 8);                  // (y, c-group)
    int y = idx8 >> 3;
    float x0 = X0[y], x1 = X1[y];
    int yb = y >> 3, y7 = y & 7;
    short8 v;
    #pragma unroll
    for (int e = 0; e < 8; ++e) {
      int c = c0 + e;
      unsigned short hv = f2bf(bv[e] + wv[2 * e] * x0 + wv[2 * e + 1] * x1);
      v[e] = (short)hv;
      St[c * BSTR + (((yb ^ (c >> 3)) & 31) << 3) + y7] = hv;
    }
    *(short8*)(hrow + (idx8 << 3)) = v;
  }
  __syncthreads();
  int lane = t & 63;
  int wid = t >> 6;
  int kq = lane >> 4, n = lane & 15;
  #pragma unroll
  for (int pp = 0; pp < 2; ++pp) {
    int p = wid + (pp << 2);
    int mt = p & 1, nt = p >> 1;               // mt: 0=cos/Yr, 1=sin/Yi
    int trow = (mt << 4) + n;                  // A: m = lane&15
    int c = (nt << 4) + n;                     // B: n = lane&15
    const unsigned short* abase = trigT + (trow << 8) + (kq << 3);
    f32x4 acc = {0.0f, 0.0f, 0.0f, 0.0f};
    #pragma unroll
    for (int k0 = 0; k0 < 8; ++k0) {
      short8 af = *(const short8*)(abase + (k0 << 5));
      int yb = (k0 << 2) + kq;
      short8 bf = *(const short8*)(&St[c * BSTR + (((yb ^ (c >> 3)) & 31) << 3)]);
      acc = __builtin_amdgcn_mfma_f32_16x16x32_bf16(af, bf, acc, 0, 0, 0);
    }
    float sgn = mt ? -0.0625f : 0.0625f;       // Yi = -sum sin * h / 16
    float* yp = Y + (row << 11) + (kq << 9) + (c << 1) + mt;
    #pragma unroll
    for (int r = 0; r < 4; ++r)
      yp[r << 7] = acc[r] * sgn;               // ky = kq*4 + r
  }
}

// F2 with 4-way x-split (R17) + coop LDS staging (R29):
// grid = (s, b, ky, cq) [2048 blocks], thread = (c16, kx).
__global__ void __launch_bounds__(256) k_f2(const float* __restrict__ Y,
                                            const float* __restrict__ costab,
                                            float* __restrict__ Xfp) {
  __shared__ float T[256];
  __shared__ float2 YS[64][16];
  int t = threadIdx.x;
  T[t] = costab[t];
  int s = blockIdx.x >> 9;             // x-chunk [0,4)
  int blk = blockIdx.x & 511;
  int bk = blk >> 2;                   // b*16 + ky
  int b = bk >> 4, ky = bk & 15;
  int cq = blk & 3;
  int x0 = s << 6;
  // phase A: coop stage.  Per x-row: 32 consecutive floats (16 float2).
  const float* yb2 = Y + ((long)(b * 256 + x0)) * 2048 + ky * 128 + (cq << 5);
  #pragma unroll
  for (int k = 0; k < 4; ++k) {
    int idx = t + (k << 8);            // [0,1024) float2 slots
    int xx = idx >> 4, f2i = idx & 15;
    YS[xx][f2i] = *(const float2*)(yb2 + (long)xx * 2048 + (f2i << 1));
  }
  __syncthreads();
  // phase B: per-thread FMA from LDS.
  int c16 = t & 15;
  int c = (cq << 4) + c16;
  int kx = t >> 4;
  float ar = 0.0f, ai = 0.0f;
  int m = (kx * x0) & 255;
  #pragma unroll 4
  for (int x = 0; x < 64; ++x) {
    float2 v = YS[x][c16];
    float cv = T[m], sv = T[(m + 192) & 255];
    ar += v.x * cv + v.y * sv;         // (yr + i yi)(c - i s)
    ai += v.y * cv - v.x * sv;
    m = (m + kx) & 255;
  }
  float* o = Xfp + (long)s * 262144 + ((long)b * 64 + c) * 512 + (kx * 16 + ky) * 2;
  o[0] = ar * 0.0625f;
  o[1] = ai * 0.0625f;
}

// reduce the 4 x-partials -> Xf (R30 re-split: the sum is o-independent;
// doing it once here removes 4 loads from k_spec's 6-load serial chain).
__global__ void __launch_bounds__(256) k_xsum(const float* __restrict__ Xfp,
                                              float* __restrict__ Xf) {
  long i = ((long)blockIdx.x * 256 + threadIdx.x) << 2;
  f32x4 a = *(const f32x4*)(Xfp + i);
  f32x4 b = *(const f32x4*)(Xfp + 262144 + i);
  f32x4 c = *(const f32x4*)(Xfp + 524288 + i);
  f32x4 d = *(const f32x4*)(Xfp + 786432 + i);
  f32x4 ab = a + b;
  f32x4 cd = c + d;
  *(f32x4*)(Xf + i) = ab + cd;
}

// mode GEMM + I1 (R19: 512 threads; R30: reads pre-reduced Xf).
// block = b*64+o [512].
// Part A: thread (m, h): partial over i in [32h,32h+32) -> LDS reduce.
// Part B: thread (x, kyh): 16 kx x 8 ky FMA; A2 stores packed as 2x short8.
__global__ void __launch_bounds__(512) k_spec(const float* __restrict__ Xf,
                                              const float* __restrict__ wr,
                                              const float* __restrict__ wi,
                                              const float* __restrict__ costab,
                                              unsigned short* __restrict__ A2) {
  __shared__ float T[256];
  __shared__ float Gr[256], Gi[256];
  __shared__ float Pr[512], Pi[512];
  int t = threadIdx.x;
  if (t < 256) T[t] = costab[t];
  int b = blockIdx.x >> 6, o = blockIdx.x & 63;
  {
    int m = t & 255, h = t >> 8;               // h in {0,1}
    float gr = 0, gi = 0;
    const float* xb = Xf + (long)b * 32768 + m * 2 + (long)(h << 5) * 512;
    const float* wrb = wr + (long)o * 256 + m + (long)(h << 5) * 16384;
    const float* wib = wi + (long)o * 256 + m + (long)(h << 5) * 16384;
    for (int i = 0; i < 32; ++i) {
      float xr = xb[(long)i * 512], xi = xb[(long)i * 512 + 1];
      float wrv = wrb[(long)i * 16384], wiv = wib[(long)i * 16384];
      gr += xr * wrv - xi * wiv;
      gi += xr * wiv + xi * wrv;
    }
    Pr[t] = gr; Pi[t] = gi;
  }
  __syncthreads();
  if (t < 256) {
    Gr[t] = Pr[t] + Pr[t + 256];
    Gi[t] = Pi[t] + Pi[t + 256];
  }
  __syncthreads();
  int x = t & 255, kyh = t >> 8;               // kyh in {0,1}
  float ar[8], ai[8];
  #pragma unroll
  for (int r = 0; r < 8; ++r) { ar[r] = 0.0f; ai[r] = 0.0f; }
  for (int kx = 0; kx < 16; ++kx) {
    int mm = (kx * x) & 255;
    float cv = T[mm], sv = T[(mm + 192) & 255];
    int gb = (kx << 4) + (kyh << 3);
    #pragma unroll
    for (int r = 0; r < 8; ++r) {
      float gr = Gr[gb + r], gi = Gi[gb + r];
      ar[r] += gr * cv - gi * sv;      // (gr+i gi)(c + i s)
      ai[r] += gr * sv + gi * cv;
    }
  }
  unsigned short* ab = A2 + ((long)(b * 256 + x) << 11) + (o << 5) + (kyh << 3);
  short8 va, vb;
  #pragma unroll
  for (int r = 0; r < 8; ++r) {
    float sc = (kyh == 0 && r == 0) ? 0.00390625f : 0.0078125f;  // 1/256, 1/128
    va[r] = (short)f2bf(ar[r] * sc);
    vb[r] = (short)f2bf(-ai[r] * sc);
  }
  *(short8*)ab = va;
  *(short8*)(ab + 16) = vb;
}

// I2 + pointwise conv + GELU (in place on hb) FUSED with next layer's F1.
// Block = one full (b,x) row, 512 threads = 8 waves (proven 1-row form).
// Phase 0: stage 256x64 h tile -> S, stride 64 + XOR swizzle (c8^y)&7.
// Phase 1: wave w = (y-half w>>2, o-strip (w&3)*16); A-frags from S; gelu ->
//          global hb + 8 ushort4 registers.
// Phase 2 (do_f1): barrier, re-stage in F1 B-layout (BSTR pad, R23),
//          barrier, F1 MFMA -> Y.
__global__ void __launch_bounds__(512) k_pw(unsigned short* __restrict__ hb,
                                            const unsigned short* __restrict__ A2,
                                            const unsigned short* __restrict__ Wt,
                                            const unsigned short* __restrict__ trig,
                                            const unsigned short* __restrict__ trigT,
                                            const float* __restrict__ pw_b,
                                            float* __restrict__ Y,
                                            int do_f1) {
  __shared__ unsigned short S[64 * BSTR];      // 33 KB; staging (16384) fits
  int t = threadIdx.x;
  long row = blockIdx.x;                       // (b,x) in [0,2048)
  int lane = t & 63;
  int wid = t >> 6;                            // 0..7
  int kq = lane >> 4, n = lane & 15;
  int half = wid >> 2;
  int o = ((wid & 3) << 4) + n;
  const unsigned short* wrow = Wt + (o << 6) + (kq << 3);
  short8 B0 = *(const short8*)(wrow);                               // c 0..31
  short8 B1 = *(const short8*)(wrow + 32);                          // c 32..63
  short8 B2 = *(const short8*)(A2 + (row << 11) + (o << 5) + (kq << 3)); // k'
  float bias = pw_b[o];
  // ---- phase 0: stage the whole row tile (256y x 64c), XOR-swizzled ----
  const unsigned short* hrow = hb + (row << 14);
  #pragma unroll
  for (int k = 0; k < 4; ++k) {
    int idx8 = t + (k << 9);                   // [0,2048) ushort8 chunks
    short8 v = *(const short8*)(hrow + (idx8 << 3));
    int yy = idx8 >> 3, c8 = idx8 & 7;
    *(short8*)(&S[(yy << 6) + (((c8 ^ yy) & 7) << 3)]) = v;
  }
  __syncthreads();                             // staging done before in-place writes
  // ---- phase 1: pw GEMM + gelu ----
  int s0 = (kq ^ n) & 7;                       // swizzled slot for c-group kq
  ushort4 res[8];
  #pragma unroll
  for (int i = 0; i < 8; ++i) {
    int m0 = i << 4;
    int yrow = (half << 7) + m0 + n;           // yrow&7 == n&7
    const unsigned short* srow = &S[yrow << 6];
    short8 a0 = *(const short8*)(srow + (s0 << 3));
    short8 a1 = *(const short8*)(srow + ((s0 ^ 4) << 3));
    short8 a2 = *(const short8*)(trig + (yrow << 5) + (kq << 3));
    f32x4 acc = {0.0f, 0.0f, 0.0f, 0.0f};
    acc = __builtin_amdgcn_mfma_f32_16x16x32_bf16(a0, B0, acc, 0, 0, 0);
    acc = __builtin_amdgcn_mfma_f32_16x16x32_bf16(a1, B1, acc, 0, 0, 0);
    acc = __builtin_amdgcn_mfma_f32_16x16x32_bf16(a2, B2, acc, 0, 0, 0);
    float v0 = acc[0] + bias;
    v0 = 0.5f * v0 * (1.0f + erff(v0 * 0.70710678118654752f));
    float v1 = acc[1] + bias;
    v1 = 0.5f * v1 * (1.0f + erff(v1 * 0.70710678118654752f));
    float v2 = acc[2] + bias;
    v2 = 0.5f * v2 * (1.0f + erff(v2 * 0.70710678118654752f));
    float v3 = acc[3] + bias;
    v3 = 0.5f * v3 * (1.0f + erff(v3 * 0.70710678118654752f));
    res[i].x = f2bf(v0); res[i].y = f2bf(v1);
    res[i].z = f2bf(v2); res[i].w = f2bf(v3);
    int y0 = (half << 7) + m0 + (kq << 2);     // rows y0..y0+3, col o
    unsigned short* ob = hb + (row << 14) + ((long)y0 << 6) + o;
    ob[0] = res[i].x; ob[64] = res[i].y; ob[128] = res[i].z; ob[192] = res[i].w;
  }
  if (do_f1) {
    __syncthreads();                           // all phase-1 S reads drained
    // ---- phase 2a: re-stage gelu tile into S in F1 B-layout (BSTR) ----
    #pragma unroll
    for (int i = 0; i < 8; ++i) {
      int y0 = (half << 7) + (i << 4) + (kq << 2);
      int yb = y0 >> 3;
      *(ushort4*)(&S[o * BSTR + (((yb ^ (o >> 3)) & 31) << 3) + (y0 & 7)]) = res[i];
    }
    __syncthreads();
    // ---- phase 2b: F1 MFMA -> Y ----
    int mt = wid & 1, nt = wid >> 1;           // 8 waves = 2 mt x 4 nt
    int trow = (mt << 4) + n;
    int c = (nt << 4) + n;
    const unsigned short* abase = trigT + (trow << 8) + (kq << 3);
    f32x4 acc = {0.0f, 0.0f, 0.0f, 0.0f};
    #pragma unroll
    for (int k0 = 0; k0 < 8; ++k0) {
      short8 af = *(const short8*)(abase + (k0 << 5));
      int yb = (k0 << 2) + kq;
      short8 bf = *(const short8*)(&S[c * BSTR + (((yb ^ (c >> 3)) & 31) << 3)]);
      acc = __builtin_amdgcn_mfma_f32_16x16x32_bf16(af, bf, acc, 0, 0, 0);
    }
    float sgn = mt ? -0.0625f : 0.0625f;
    float* yp = Y + (row << 11) + (kq << 9) + (c << 1) + mt;
    #pragma unroll
    for (int r = 0; r < 4; ++r)
      yp[r << 7] = acc[r] * sgn;               // ky = kq*4 + r
  }
}

// output: hidden = H @ o1^T (bf16 MFMA, K=64), bias+gelu, then o2 dot via
// per-lane scale + butterfly shfl_xor over the quad's 16 columns.
__global__ void __launch_bounds__(256) k_out(const unsigned short* __restrict__ hb,
                                             const unsigned short* __restrict__ o1wbf,
                                             const float* __restrict__ o1_b,
                                             const float* __restrict__ o2_w,
                                             const float* __restrict__ o2_b,
                                             float* __restrict__ out) {
  __shared__ unsigned short S[128 * 88];
  int t = threadIdx.x;
  long row = blockIdx.x >> 1;                  // (b,x) in [0,2048)
  int half = blockIdx.x & 1;
  const unsigned short* hbase = hb + (row << 14) + (half << 13);
  #pragma unroll
  for (int k = 0; k < 4; ++k) {
    int idx8 = t + (k << 8);
    short8 v = *(const short8*)(hbase + (idx8 << 3));
    int yy = idx8 >> 3, c8 = idx8 & 7;
    *(short8*)(&S[yy * 88 + (c8 << 3)]) = v;
  }
  int lane = t & 63;
  int kq = lane >> 4;
  int n = lane & 15;
  int wid = t >> 6;                            // rows [32*wid, 32*wid+32)
  const unsigned short* w0 = o1wbf + (n << 6) + (kq << 3);         // o = n
  const unsigned short* w1 = o1wbf + ((n + 16) << 6) + (kq << 3);  // o = n+16
  short8 B0a = *(const short8*)(w0);
  short8 B0b = *(const short8*)(w0 + 32);
  short8 B1a = *(const short8*)(w1);
  short8 B1b = *(const short8*)(w1 + 32);
  float b0 = o1_b[n], b1 = o1_b[n + 16];
  float g0 = o2_w[n], g1 = o2_w[n + 16];
  float ob2 = o2_b[0];
  __syncthreads();
  float* outp = out + row * 256 + (half << 7);
  #pragma unroll
  for (int mt = 0; mt < 2; ++mt) {
    int m0 = (wid << 5) + (mt << 4);
    const unsigned short* srow = &S[(m0 + n) * 88 + (kq << 3)];
    short8 a0 = *(const short8*)(srow);
    short8 a1 = *(const short8*)(srow + 32);
    f32x4 c0 = {0.0f, 0.0f, 0.0f, 0.0f}, c1 = {0.0f, 0.0f, 0.0f, 0.0f};
    c0 = __builtin_amdgcn_mfma_f32_16x16x32_bf16(a0, B0a, c0, 0, 0, 0);
    c0 = __builtin_amdgcn_mfma_f32_16x16x32_bf16(a1, B0b, c0, 0, 0, 0);
    c1 = __builtin_amdgcn_mfma_f32_16x16x32_bf16(a0, B1a, c1, 0, 0, 0);
    c1 = __builtin_amdgcn_mfma_f32_16x16x32_bf16(a1, B1b, c1, 0, 0, 0);
    #pragma unroll
    for (int r = 0; r < 4; ++r) {
      float v0 = c0[r] + b0;
      v0 = 0.5f * v0 * (1.0f + erff(v0 * 0.70710678118654752f));
      float v1 = c1[r] + b1;
      v1 = 0.5f * v1 * (1.0f + erff(v1 * 0.70710678118654752f));
      float s = v0 * g0 + v1 * g1;
      s += __shfl_xor(s, 1);
      s += __shfl_xor(s, 2);
      s += __shfl_xor(s, 4);
      s += __shfl_xor(s, 8);
      if (n == 0) outp[m0 + (kq << 2) + r] = s + ob2;
    }
  }
}

extern "C" void kernel_launch(void* const* d_in, const int* in_sizes, int n_in,
                              void* d_out, int out_size, void* d_ws, size_t ws_size,
                              hipStream_t stream) {
  const float* x       = (const float*)d_in[0];
  const float* in_w    = (const float*)d_in[1];
  const float* in_b    = (const float*)d_in[2];
  const float* spec_wr = (const float*)d_in[3];
  const float* spec_wi = (const float*)d_in[4];
  const float* pw_w    = (const float*)d_in[5];
  const float* pw_b    = (const float*)d_in[6];
  const float* o1_w    = (const float*)d_in[7];
  const float* o1_b    = (const float*)d_in[8];
  const float* o2_w    = (const float*)d_in[9];
  const float* o2_b    = (const float*)d_in[10];
  float* ws = (float*)d_ws;
  unsigned short* hb = (unsigned short*)(ws + OFF_H);
  unsigned short* A2 = (unsigned short*)(ws + OFF_A2);
  float* Xfp    = ws + OFF_XFP;
  float* Y      = ws + OFF_YA;
  float* Xf     = ws + OFF_XF;
  float* costab = ws + OFF_TAB;
  unsigned short* o1wbf = (unsigned short*)(ws + OFF_O1W);
  unsigned short* trig = (unsigned short*)(ws + OFF_TRIG);
  unsigned short* wt   = (unsigned short*)(ws + OFF_WT);
  unsigned short* trigT = (unsigned short*)(ws + OFF_TRIGT);
  float* out = (float*)d_out;

  k_init<<<73, 256, 0, stream>>>(ws, pw_w, o1_w);
  k_f1<<<2048, 256, 0, stream>>>(x, in_w, in_b, trigT, hb, Y);  // +input conv
  for (int l = 0; l < NLAYER; ++l) {
    k_f2<<<2048, 256, 0, stream>>>(Y, costab, Xfp);
    k_xsum<<<256, 256, 0, stream>>>(Xfp, Xf);
    k_spec<<<512, 512, 0, stream>>>(Xf, spec_wr + (long)l * 1048576,
                                    spec_wi + (long)l * 1048576, costab, A2);
    k_pw<<<2048, 512, 0, stream>>>(hb, A2, wt + l * 4096, trig, trigT,
                                   pw_b + l * 64, Y, (l < NLAYER - 1) ? 1 : 0);
  }
  k_out<<<4096, 256, 0, stream>>>(hb, o1wbf, o1_b, o2_w, o2_b, out);
}

// Round 18
// 400.912 us; speedup vs baseline: 1.2594x; 1.0110x over previous
//
#include <hip/hip_runtime.h>
#include <math.h>

// FNO2d: B=8, CIN=2, COUT=1, W0=64, modes 16x16, NL=4, H=W=256
// h stored channels-last BF16: [B][H][W][64] ushort.
// Y  (F1 out, fp32): [B][H(x)][16ky][64c][2]
// Xfp (F2 out, fp32): 4 x-partials of Xf; Xf (fp32): [B][64c][256m][2]
// A2 (spec out, bf16): [B*256 rows][64o][32k']
// Trig  (bf16): [256y][32k'] (A-frags for k_pw I2)
// TrigT (bf16): [32 rows][256y] (A-frags for F1; rows 0-15 cos, 16-31 sin)
// k_f1 (layer 0 only) = input 1x1 conv + bf16 MFMA GEMM Y = TrigT @ H.
// k_pw = bf16 MFMA GEMM [H | Trig] @ [pw_w^T ; A2] + bias -> gelu -> hb,
//        FUSED with next layer's F1 via LDS (stage -> pw -> re-stage -> F1).
// k_out = bf16 MFMA GEMM (H @ o1^T) + gelu + cross-lane o2 dot.
//
// HARD-WON RULES:
//  - (R2/R3/R5) NEVER use min-waves arg of __launch_bounds__ with per-thread
//    accumulator arrays: backend spills to hit the VGPR tier.
//  - (R4/R6/R9) per-thread accs + uniform weight streaming via s_load is
//    latency-bound; keep weights in VGPR MFMA B-frags.
//  - (R11) grid must cover 256 CUs.  (R12) fuse pairs sharing a row tile.
//  - (R13) in-place kernels must stage the ENTIRE input tile (LDS or regs)
//    behind the first in-place write -- no direct global reads after.
//  - (R16) fast A-S-erf gelu REGRESSED (TRANS-pipe rcp+exp); erff kept.
//  - (R17) thin-grid latency kernels: k_f2 4-way x-split -> +19us.
//  - (R19) k_spec widened to 512 thr -> +7us.
//  - (R20) k_in->k_f1 fusion kept.
//  - (R21) k_pw 2-row/block pipeline REGRESSED (VGPR cliff); 1 row/block.
//  - (R22) containers throttle up to 25%; judge by clock-independent
//    counters (bytes, conflict counts) across containers.
//  - (R23) BSTR=264 pad: conflicts 7.34M -> 1.05M, k_pw 52.6 -> 49.6us.
//  - (R26) k_f2 8-way split doubled k_spec's reduce chain: REGRESSED.
//  - (R28) R27 "write amplification" was an arithmetic error; R12 base.
//  - (R29) k_f2 coop LDS staging (16x redundant kx-independent loads):
//    463->444us.
//  - (R30) k_spec's o-independent partial sum re-split to k_xsum:
//    444->405us.  All wins come from address-math audits.
//  - (R31) k_pw phase-1's in-loop GLOBAL trig loads (VGPR 36 can't hold 8
//    prefetched frags -> staggered ~200cy L2 chains inside the MFMA loop).
//    Stage trig to LDS in phase 0 (TPAD=36: n*18 mod 32 spans 16 banks ->
//    conflict-free).  LDS 33.8->52.2KB.  Revert trigger: k_pw >= 52us.
//  - (R32, this round) R31's bench was an infra failure (container died
//    twice; same signature as R4 which passed on resubmit).  Audit clean
//    (LDS 52224<64K, TS bounds exact, no barrier/race changes).
//    Resubmitted unchanged.

#define NLAYER 4

// ws offsets in floats
#define OFF_H     0L                  // hb ushorts, floats [0, 16.8M)
#define OFF_A2    16777216L           // A2 bf16: 4.2M ush = 2.1M fl
#define OFF_XFP   18874368L           // 4 x 262144 fl x-partials (A2 gap)
#define OFF_YA    33554432L           // Y fp32 (4194304 fl)
#define OFF_XF    37748736L           // 262144 fl (reduced Xf)
#define OFF_TAB   38010880L           // 256 fl
#define OFF_O1W   38011136L           // o1 bf16: 2048 ush = 1024 fl
#define OFF_TRIG  38013184L           // 8192 ush = 4096 fl
#define OFF_WT    38017280L           // 16384 ush = 8192 fl
#define OFF_TRIGT 38025472L           // 8192 ush = 4096 fl
#define WS_FLOATS 38029568L

// F1 B-layout c-stride in ushorts (R23: 264 = 132 words, %32 = 4 -> 4-bank
// shift per c; 256 = 4 full wraps -> 8-way conflicts)
#define BSTR 264
// Trig LDS row stride in ushorts (R31: 36 = 18 words; lane-row stride
// n*18 mod 32 spans all 16 residues -> conflict-free b128 reads)
#define TPAD 36

typedef __attribute__((ext_vector_type(8))) short short8;
typedef __attribute__((ext_vector_type(4))) float f32x4;

__device__ __forceinline__ unsigned short f2bf(float f) {
  unsigned int u = __float_as_uint(f);
  u += 0x7FFF + ((u >> 16) & 1);          // round-to-nearest-even
  return (unsigned short)(u >> 16);
}

__global__ void k_init(float* __restrict__ ws, const float* __restrict__ pw_w,
                       const float* __restrict__ o1_w) {
  float* costab = ws + OFF_TAB;
  unsigned short* o1wbf = (unsigned short*)(ws + OFF_O1W);
  unsigned short* trig = (unsigned short*)(ws + OFF_TRIG);
  unsigned short* wt = (unsigned short*)(ws + OFF_WT);
  unsigned short* trigT = (unsigned short*)(ws + OFF_TRIGT);
  int t = blockIdx.x * blockDim.x + threadIdx.x;
  int stride = gridDim.x * blockDim.x;
  for (int m = t; m < 256; m += stride)
    costab[m] = (float)cos((double)m * (3.14159265358979323846 / 128.0));
  for (int idx = t; idx < 32 * 64; idx += stride)
    o1wbf[idx] = f2bf(o1_w[idx]);               // [o][c]
  for (int idx = t; idx < 256 * 32; idx += stride) {
    int y = idx >> 5, k = idx & 31;
    int mm = ((k & 15) * y) & 255;
    double ang = (double)mm * (3.14159265358979323846 / 128.0);
    double v = (k < 16) ? cos(ang) : sin(ang);
    trig[idx] = f2bf((float)v);
  }
  for (int idx = t; idx < 32 * 256; idx += stride) {   // trigT[r][y]
    int r = idx >> 8, y = idx & 255;
    int mm = ((r & 15) * y) & 255;
    double ang = (double)mm * (3.14159265358979323846 / 128.0);
    double v = (r < 16) ? cos(ang) : sin(ang);
    trigT[idx] = f2bf((float)v);
  }
  for (int idx = t; idx < NLAYER * 64 * 64; idx += stride)
    wt[idx] = f2bf(pw_w[idx]);                  // [l][o][c]
}

// F1 + input conv (R20 fused). Block = one (b,x) row.
__global__ void __launch_bounds__(256) k_f1(const float* __restrict__ x,
                                            const float* __restrict__ in_w,
                                            const float* __restrict__ in_b,
                                            const unsigned short* __restrict__ trigT,
                                            unsigned short* __restrict__ hb,
                                            float* __restrict__ Y) {
  __shared__ unsigned short St[64 * BSTR];
  __shared__ float X0[256], X1[256];
  int t = threadIdx.x;
  long row = blockIdx.x;
  long b = row >> 8, xr = row & 255;
  const float* xb = x + b * 131072 + (xr << 8);
  X0[t] = xb[t];
  X1[t] = xb[65536 + t];
  int c0 = (t & 7) << 3;                       // fixed 8-channel group
  float wv[16], bv[8];
  #pragma unroll
  for (int e = 0; e < 8; ++e) {
    wv[2 * e]     = in_w[(c0 + e) * 2];
    wv[2 * e + 1] = in_w[(c0 + e) * 2 + 1];
    bv[e]         = in_b[c0 + e];
  }
  __syncthreads();
  unsigned short* hrow = hb + (row << 14);
  #pragma unroll
  for (int kk = 0; kk < 8; ++kk) {
    int idx8 = t + (kk << 8);                  // (y, c-group)
    int y = idx8 >> 3;
    float x0 = X0[y], x1 = X1[y];
    int yb = y >> 3, y7 = y & 7;
    short8 v;
    #pragma unroll
    for (int e = 0; e < 8; ++e) {
      int c = c0 + e;
      unsigned short hv = f2bf(bv[e] + wv[2 * e] * x0 + wv[2 * e + 1] * x1);
      v[e] = (short)hv;
      St[c * BSTR + (((yb ^ (c >> 3)) & 31) << 3) + y7] = hv;
    }
    *(short8*)(hrow + (idx8 << 3)) = v;
  }
  __syncthreads();
  int lane = t & 63;
  int wid = t >> 6;
  int kq = lane >> 4, n = lane & 15;
  #pragma unroll
  for (int pp = 0; pp < 2; ++pp) {
    int p = wid + (pp << 2);
    int mt = p & 1, nt = p >> 1;               // mt: 0=cos/Yr, 1=sin/Yi
    int trow = (mt << 4) + n;                  // A: m = lane&15
    int c = (nt << 4) + n;                     // B: n = lane&15
    const unsigned short* abase = trigT + (trow << 8) + (kq << 3);
    f32x4 acc = {0.0f, 0.0f, 0.0f, 0.0f};
    #pragma unroll
    for (int k0 = 0; k0 < 8; ++k0) {
      short8 af = *(const short8*)(abase + (k0 << 5));
      int yb = (k0 << 2) + kq;
      short8 bf = *(const short8*)(&St[c * BSTR + (((yb ^ (c >> 3)) & 31) << 3)]);
      acc = __builtin_amdgcn_mfma_f32_16x16x32_bf16(af, bf, acc, 0, 0, 0);
    }
    float sgn = mt ? -0.0625f : 0.0625f;       // Yi = -sum sin * h / 16
    float* yp = Y + (row << 11) + (kq << 9) + (c << 1) + mt;
    #pragma unroll
    for (int r = 0; r < 4; ++r)
      yp[r << 7] = acc[r] * sgn;               // ky = kq*4 + r
  }
}

// F2 with 4-way x-split (R17) + coop LDS staging (R29):
// grid = (s, b, ky, cq) [2048 blocks], thread = (c16, kx).
__global__ void __launch_bounds__(256) k_f2(const float* __restrict__ Y,
                                            const float* __restrict__ costab,
                                            float* __restrict__ Xfp) {
  __shared__ float T[256];
  __shared__ float2 YS[64][16];
  int t = threadIdx.x;
  T[t] = costab[t];
  int s = blockIdx.x >> 9;             // x-chunk [0,4)
  int blk = blockIdx.x & 511;
  int bk = blk >> 2;                   // b*16 + ky
  int b = bk >> 4, ky = bk & 15;
  int cq = blk & 3;
  int x0 = s << 6;
  // phase A: coop stage.  Per x-row: 32 consecutive floats (16 float2).
  const float* yb2 = Y + ((long)(b * 256 + x0)) * 2048 + ky * 128 + (cq << 5);
  #pragma unroll
  for (int k = 0; k < 4; ++k) {
    int idx = t + (k << 8);            // [0,1024) float2 slots
    int xx = idx >> 4, f2i = idx & 15;
    YS[xx][f2i] = *(const float2*)(yb2 + (long)xx * 2048 + (f2i << 1));
  }
  __syncthreads();
  // phase B: per-thread FMA from LDS.
  int c16 = t & 15;
  int c = (cq << 4) + c16;
  int kx = t >> 4;
  float ar = 0.0f, ai = 0.0f;
  int m = (kx * x0) & 255;
  #pragma unroll 4
  for (int x = 0; x < 64; ++x) {
    float2 v = YS[x][c16];
    float cv = T[m], sv = T[(m + 192) & 255];
    ar += v.x * cv + v.y * sv;         // (yr + i yi)(c - i s)
    ai += v.y * cv - v.x * sv;
    m = (m + kx) & 255;
  }
  float* o = Xfp + (long)s * 262144 + ((long)b * 64 + c) * 512 + (kx * 16 + ky) * 2;
  o[0] = ar * 0.0625f;
  o[1] = ai * 0.0625f;
}

// reduce the 4 x-partials -> Xf (R30: the sum is o-independent; doing it
// once here removes 4 loads from k_spec's serial chain).
__global__ void __launch_bounds__(256) k_xsum(const float* __restrict__ Xfp,
                                              float* __restrict__ Xf) {
  long i = ((long)blockIdx.x * 256 + threadIdx.x) << 2;
  f32x4 a = *(const f32x4*)(Xfp + i);
  f32x4 b = *(const f32x4*)(Xfp + 262144 + i);
  f32x4 c = *(const f32x4*)(Xfp + 524288 + i);
  f32x4 d = *(const f32x4*)(Xfp + 786432 + i);
  f32x4 ab = a + b;
  f32x4 cd = c + d;
  *(f32x4*)(Xf + i) = ab + cd;
}

// mode GEMM + I1 (R19: 512 threads; R30: reads pre-reduced Xf).
// block = b*64+o [512].
__global__ void __launch_bounds__(512) k_spec(const float* __restrict__ Xf,
                                              const float* __restrict__ wr,
                                              const float* __restrict__ wi,
                                              const float* __restrict__ costab,
                                              unsigned short* __restrict__ A2) {
  __shared__ float T[256];
  __shared__ float Gr[256], Gi[256];
  __shared__ float Pr[512], Pi[512];
  int t = threadIdx.x;
  if (t < 256) T[t] = costab[t];
  int b = blockIdx.x >> 6, o = blockIdx.x & 63;
  {
    int m = t & 255, h = t >> 8;               // h in {0,1}
    float gr = 0, gi = 0;
    const float* xb = Xf + (long)b * 32768 + m * 2 + (long)(h << 5) * 512;
    const float* wrb = wr + (long)o * 256 + m + (long)(h << 5) * 16384;
    const float* wib = wi + (long)o * 256 + m + (long)(h << 5) * 16384;
    for (int i = 0; i < 32; ++i) {
      float xr = xb[(long)i * 512], xi = xb[(long)i * 512 + 1];
      float wrv = wrb[(long)i * 16384], wiv = wib[(long)i * 16384];
      gr += xr * wrv - xi * wiv;
      gi += xr * wiv + xi * wrv;
    }
    Pr[t] = gr; Pi[t] = gi;
  }
  __syncthreads();
  if (t < 256) {
    Gr[t] = Pr[t] + Pr[t + 256];
    Gi[t] = Pi[t] + Pi[t + 256];
  }
  __syncthreads();
  int x = t & 255, kyh = t >> 8;               // kyh in {0,1}
  float ar[8], ai[8];
  #pragma unroll
  for (int r = 0; r < 8; ++r) { ar[r] = 0.0f; ai[r] = 0.0f; }
  for (int kx = 0; kx < 16; ++kx) {
    int mm = (kx * x) & 255;
    float cv = T[mm], sv = T[(mm + 192) & 255];
    int gb = (kx << 4) + (kyh << 3);
    #pragma unroll
    for (int r = 0; r < 8; ++r) {
      float gr = Gr[gb + r], gi = Gi[gb + r];
      ar[r] += gr * cv - gi * sv;      // (gr+i gi)(c + i s)
      ai[r] += gr * sv + gi * cv;
    }
  }
  unsigned short* ab = A2 + ((long)(b * 256 + x) << 11) + (o << 5) + (kyh << 3);
  short8 va, vb;
  #pragma unroll
  for (int r = 0; r < 8; ++r) {
    float sc = (kyh == 0 && r == 0) ? 0.00390625f : 0.0078125f;  // 1/256, 1/128
    va[r] = (short)f2bf(ar[r] * sc);
    vb[r] = (short)f2bf(-ai[r] * sc);
  }
  *(short8*)ab = va;
  *(short8*)(ab + 16) = vb;
}

// I2 + pointwise conv + GELU (in place on hb) FUSED with next layer's F1.
// Block = one full (b,x) row, 512 threads = 8 waves (proven 1-row form).
// Phase 0: stage 256x64 h tile -> S (XOR swizzle (c8^y)&7) AND trig
//          (16KB, TPAD rows) -> TS.
// Phase 1: wave w = (y-half w>>2, o-strip (w&3)*16); A-frags from S,
//          trig frags from TS (conflict-free, R31); gelu -> hb + res regs.
// Phase 2 (do_f1): barrier, re-stage in F1 B-layout (BSTR pad, R23),
//          barrier, F1 MFMA -> Y.
__global__ void __launch_bounds__(512) k_pw(unsigned short* __restrict__ hb,
                                            const unsigned short* __restrict__ A2,
                                            const unsigned short* __restrict__ Wt,
                                            const unsigned short* __restrict__ trig,
                                            const unsigned short* __restrict__ trigT,
                                            const float* __restrict__ pw_b,
                                            float* __restrict__ Y,
                                            int do_f1) {
  __shared__ unsigned short S[64 * BSTR];      // 33 KB; F1 B-tile reuses it
  __shared__ unsigned short TS[256 * TPAD];    // 18 KB trig cache (R31)
  int t = threadIdx.x;
  long row = blockIdx.x;                       // (b,x) in [0,2048)
  int lane = t & 63;
  int wid = t >> 6;                            // 0..7
  int kq = lane >> 4, n = lane & 15;
  int half = wid >> 2;
  int o = ((wid & 3) << 4) + n;
  const unsigned short* wrow = Wt + (o << 6) + (kq << 3);
  short8 B0 = *(const short8*)(wrow);                               // c 0..31
  short8 B1 = *(const short8*)(wrow + 32);                          // c 32..63
  short8 B2 = *(const short8*)(A2 + (row << 11) + (o << 5) + (kq << 3)); // k'
  float bias = pw_b[o];
  // ---- phase 0: stage h row tile (XOR-swizzled) + trig (TPAD rows) ----
  const unsigned short* hrow = hb + (row << 14);
  #pragma unroll
  for (int k = 0; k < 4; ++k) {
    int idx8 = t + (k << 9);                   // [0,2048) ushort8 chunks
    short8 v = *(const short8*)(hrow + (idx8 << 3));
    int yy = idx8 >> 3, c8 = idx8 & 7;
    *(short8*)(&S[(yy << 6) + (((c8 ^ yy) & 7) << 3)]) = v;
  }
  #pragma unroll
  for (int k = 0; k < 2; ++k) {
    int idx8 = t + (k << 9);                   // [0,1024): trig 8-chunks
    short8 v = *(const short8*)(trig + (idx8 << 3));
    int yy = idx8 >> 2, sl = idx8 & 3;
    *(short8*)(&TS[yy * TPAD + (sl << 3)]) = v;
  }
  __syncthreads();                             // staging done before in-place writes
  // ---- phase 1: pw GEMM + gelu ----
  int s0 = (kq ^ n) & 7;                       // swizzled slot for c-group kq
  ushort4 res[8];
  #pragma unroll
  for (int i = 0; i < 8; ++i) {
    int m0 = i << 4;
    int yrow = (half << 7) + m0 + n;           // yrow&7 == n&7
    const unsigned short* srow = &S[yrow << 6];
    short8 a0 = *(const short8*)(srow + (s0 << 3));
    short8 a1 = *(const short8*)(srow + ((s0 ^ 4) << 3));
    short8 a2 = *(const short8*)(&TS[yrow * TPAD + (kq << 3)]);
    f32x4 acc = {0.0f, 0.0f, 0.0f, 0.0f};
    acc = __builtin_amdgcn_mfma_f32_16x16x32_bf16(a0, B0, acc, 0, 0, 0);
    acc = __builtin_amdgcn_mfma_f32_16x16x32_bf16(a1, B1, acc, 0, 0, 0);
    acc = __builtin_amdgcn_mfma_f32_16x16x32_bf16(a2, B2, acc, 0, 0, 0);
    float v0 = acc[0] + bias;
    v0 = 0.5f * v0 * (1.0f + erff(v0 * 0.70710678118654752f));
    float v1 = acc[1] + bias;
    v1 = 0.5f * v1 * (1.0f + erff(v1 * 0.70710678118654752f));
    float v2 = acc[2] + bias;
    v2 = 0.5f * v2 * (1.0f + erff(v2 * 0.70710678118654752f));
    float v3 = acc[3] + bias;
    v3 = 0.5f * v3 * (1.0f + erff(v3 * 0.70710678118654752f));
    res[i].x = f2bf(v0); res[i].y = f2bf(v1);
    res[i].z = f2bf(v2); res[i].w = f2bf(v3);
    int y0 = (half << 7) + m0 + (kq << 2);     // rows y0..y0+3, col o
    unsigned short* ob = hb + (row << 14) + ((long)y0 << 6) + o;
    ob[0] = res[i].x; ob[64] = res[i].y; ob[128] = res[i].z; ob[192] = res[i].w;
  }
  if (do_f1) {
    __syncthreads();                           // all phase-1 S reads drained
    // ---- phase 2a: re-stage gelu tile into S in F1 B-layout (BSTR) ----
    #pragma unroll
    for (int i = 0; i < 8; ++i) {
      int y0 = (half << 7) + (i << 4) + (kq << 2);
      int yb = y0 >> 3;
      *(ushort4*)(&S[o * BSTR + (((yb ^ (o >> 3)) & 31) << 3) + (y0 & 7)]) = res[i];
    }
    __syncthreads();
    // ---- phase 2b: F1 MFMA -> Y ----
    int mt = wid & 1, nt = wid >> 1;           // 8 waves = 2 mt x 4 nt
    int trow = (mt << 4) + n;
    int c = (nt << 4) + n;
    const unsigned short* abase = trigT + (trow << 8) + (kq << 3);
    f32x4 acc = {0.0f, 0.0f, 0.0f, 0.0f};
    #pragma unroll
    for (int k0 = 0; k0 < 8; ++k0) {
      short8 af = *(const short8*)(abase + (k0 << 5));
      int yb = (k0 << 2) + kq;
      short8 bf = *(const short8*)(&S[c * BSTR + (((yb ^ (c >> 3)) & 31) << 3)]);
      acc = __builtin_amdgcn_mfma_f32_16x16x32_bf16(af, bf, acc, 0, 0, 0);
    }
    float sgn = mt ? -0.0625f : 0.0625f;
    float* yp = Y + (row << 11) + (kq << 9) + (c << 1) + mt;
    #pragma unroll
    for (int r = 0; r < 4; ++r)
      yp[r << 7] = acc[r] * sgn;               // ky = kq*4 + r
  }
}

// output: hidden = H @ o1^T (bf16 MFMA, K=64), bias+gelu, then o2 dot via
// per-lane scale + butterfly shfl_xor over the quad's 16 columns.
__global__ void __launch_bounds__(256) k_out(const unsigned short* __restrict__ hb,
                                             const unsigned short* __restrict__ o1wbf,
                                             const float* __restrict__ o1_b,
                                             const float* __restrict__ o2_w,
                                             const float* __restrict__ o2_b,
                                             float* __restrict__ out) {
  __shared__ unsigned short S[128 * 88];
  int t = threadIdx.x;
  long row = blockIdx.x >> 1;                  // (b,x) in [0,2048)
  int half = blockIdx.x & 1;
  const unsigned short* hbase = hb + (row << 14) + (half << 13);
  #pragma unroll
  for (int k = 0; k < 4; ++k) {
    int idx8 = t + (k << 8);
    short8 v = *(const short8*)(hbase + (idx8 << 3));
    int yy = idx8 >> 3, c8 = idx8 & 7;
    *(short8*)(&S[yy * 88 + (c8 << 3)]) = v;
  }
  int lane = t & 63;
  int kq = lane >> 4;
  int n = lane & 15;
  int wid = t >> 6;                            // rows [32*wid, 32*wid+32)
  const unsigned short* w0 = o1wbf + (n << 6) + (kq << 3);         // o = n
  const unsigned short* w1 = o1wbf + ((n + 16) << 6) + (kq << 3);  // o = n+16
  short8 B0a = *(const short8*)(w0);
  short8 B0b = *(const short8*)(w0 + 32);
  short8 B1a = *(const short8*)(w1);
  short8 B1b = *(const short8*)(w1 + 32);
  float b0 = o1_b[n], b1 = o1_b[n + 16];
  float g0 = o2_w[n], g1 = o2_w[n + 16];
  float ob2 = o2_b[0];
  __syncthreads();
  float* outp = out + row * 256 + (half << 7);
  #pragma unroll
  for (int mt = 0; mt < 2; ++mt) {
    int m0 = (wid << 5) + (mt << 4);
    const unsigned short* srow = &S[(m0 + n) * 88 + (kq << 3)];
    short8 a0 = *(const short8*)(srow);
    short8 a1 = *(const short8*)(srow + 32);
    f32x4 c0 = {0.0f, 0.0f, 0.0f, 0.0f}, c1 = {0.0f, 0.0f, 0.0f, 0.0f};
    c0 = __builtin_amdgcn_mfma_f32_16x16x32_bf16(a0, B0a, c0, 0, 0, 0);
    c0 = __builtin_amdgcn_mfma_f32_16x16x32_bf16(a1, B0b, c0, 0, 0, 0);
    c1 = __builtin_amdgcn_mfma_f32_16x16x32_bf16(a0, B1a, c1, 0, 0, 0);
    c1 = __builtin_amdgcn_mfma_f32_16x16x32_bf16(a1, B1b, c1, 0, 0, 0);
    #pragma unroll
    for (int r = 0; r < 4; ++r) {
      float v0 = c0[r] + b0;
      v0 = 0.5f * v0 * (1.0f + erff(v0 * 0.70710678118654752f));
      float v1 = c1[r] + b1;
      v1 = 0.5f * v1 * (1.0f + erff(v1 * 0.70710678118654752f));
      float s = v0 * g0 + v1 * g1;
      s += __shfl_xor(s, 1);
      s += __shfl_xor(s, 2);
      s += __shfl_xor(s, 4);
      s += __shfl_xor(s, 8);
      if (n == 0) outp[m0 + (kq << 2) + r] = s + ob2;
    }
  }
}

extern "C" void kernel_launch(void* const* d_in, const int* in_sizes, int n_in,
                              void* d_out, int out_size, void* d_ws, size_t ws_size,
                              hipStream_t stream) {
  const float* x       = (const float*)d_in[0];
  const float* in_w    = (const float*)d_in[1];
  const float* in_b    = (const float*)d_in[2];
  const float* spec_wr = (const float*)d_in[3];
  const float* spec_wi = (const float*)d_in[4];
  const float* pw_w    = (const float*)d_in[5];
  const float* pw_b    = (const float*)d_in[6];
  const float* o1_w    = (const float*)d_in[7];
  const float* o1_b    = (const float*)d_in[8];
  const float* o2_w    = (const float*)d_in[9];
  const float* o2_b    = (const float*)d_in[10];
  float* ws = (float*)d_ws;
  unsigned short* hb = (unsigned short*)(ws + OFF_H);
  unsigned short* A2 = (unsigned short*)(ws + OFF_A2);
  float* Xfp    = ws + OFF_XFP;
  float* Y      = ws + OFF_YA;
  float* Xf     = ws + OFF_XF;
  float* costab = ws + OFF_TAB;
  unsigned short* o1wbf = (unsigned short*)(ws + OFF_O1W);
  unsigned short* trig = (unsigned short*)(ws + OFF_TRIG);
  unsigned short* wt   = (unsigned short*)(ws + OFF_WT);
  unsigned short* trigT = (unsigned short*)(ws + OFF_TRIGT);
  float* out = (float*)d_out;

  k_init<<<73, 256, 0, stream>>>(ws, pw_w, o1_w);
  k_f1<<<2048, 256, 0, stream>>>(x, in_w, in_b, trigT, hb, Y);  // +input conv
  for (int l = 0; l < NLAYER; ++l) {
    k_f2<<<2048, 256, 0, stream>>>(Y, costab, Xfp);
    k_xsum<<<256, 256, 0, stream>>>(Xfp, Xf);
    k_spec<<<512, 512, 0, stream>>>(Xf, spec_wr + (long)l * 1048576,
                                    spec_wi + (long)l * 1048576, costab, A2);
    k_pw<<<2048, 512, 0, stream>>>(hb, A2, wt + l * 4096, trig, trigT,
                                   pw_b + l * 64, Y, (l < NLAYER - 1) ? 1 : 0);
  }
  k_out<<<4096, 256, 0, stream>>>(hb, o1wbf, o1_b, o2_w, o2_b, out);
}

// Round 19
// 381.689 us; speedup vs baseline: 1.3228x; 1.0504x over previous
//
#include <hip/hip_runtime.h>
#include <math.h>

// FNO2d: B=8, CIN=2, COUT=1, W0=64, modes 16x16, NL=4, H=W=256
// h stored channels-last BF16: [B][H][W][64] ushort.
// Y  (F1 out, fp32): [B][H(x)][16ky][64c][2]
// Xfp (F2 out, fp32): 4 x-partials of Xf; Xf (fp32): [B][64c][256m][2]
// A2 (spec out, bf16): [B*256 rows][64o][32k']
// Trig  (bf16): [256y][32k'] (A-frags for k_pw I2)
// TrigT (bf16): [32 rows][256y] (A-frags for F1; rows 0-15 cos, 16-31 sin)
// k_f1 (layer 0 only) = input 1x1 conv + bf16 MFMA GEMM Y = TrigT @ H.
// k_pw = bf16 MFMA GEMM [H | Trig] @ [pw_w^T ; A2] + bias -> gelu -> hb,
//        FUSED with next layer's F1 via LDS (stage -> pw -> re-stage -> F1).
// k_out = bf16 MFMA GEMM (H @ o1^T) + gelu + cross-lane o2 dot.
//
// HARD-WON RULES:
//  - (R2/R3/R5) NEVER use min-waves arg of __launch_bounds__ with per-thread
//    accumulator arrays: backend spills to hit the VGPR tier.
//  - (R4/R6/R9) per-thread accs + uniform weight streaming via s_load is
//    latency-bound; keep weights in VGPR MFMA B-frags.
//  - (R11) grid must cover 256 CUs.  (R12) fuse pairs sharing a row tile.
//  - (R13) in-place kernels must stage the ENTIRE input tile (LDS or regs)
//    behind the first in-place write -- no direct global reads after.
//  - (R16) fast A-S-erf gelu REGRESSED (TRANS-pipe rcp+exp); erff kept.
//  - (R17) thin-grid latency kernels: k_f2 4-way x-split -> +19us.
//  - (R19) k_spec widened to 512 thr -> +7us.
//  - (R20) k_in->k_f1 fusion kept.
//  - (R21) k_pw 2-row/block pipeline REGRESSED (VGPR cliff); 1 row/block.
//  - (R22) containers throttle up to 25%; judge by clock-independent
//    counters (bytes, conflict counts) across containers.
//  - (R23) BSTR=264 pad: conflicts 7.34M -> 1.05M, k_pw 52.6 -> 49.6us.
//  - (R26) k_f2 8-way split doubled k_spec's reduce chain: REGRESSED.
//  - (R28) R27 "write amplification" was an arithmetic error; R12 base.
//  - (R29) k_f2 coop LDS staging (16x redundant kx-independent loads):
//    463->444us.
//  - (R30) k_spec's o-independent partial sum re-split to k_xsum:
//    444->405us.
//  - (R31) k_pw phase-1 trig staged to LDS (TPAD=36): in-loop global loads
//    at VGPR~40 were un-prefetchable ~200cy L2 chains.  k_pw 51.5->45.8,
//    total 405->401.
//  - (R33, this round) SAME defect in k_pw phase 2b and k_f1: trigT global
//    loads inside the MFMA loops.  k_pw: re-stage trigT into the dead TS
//    buffer during phase 2a (32x264 rows fits 8448<=9216; existing barriers
//    sequence the reuse; word addr 132*trow+4*kq -> uniform 8 lanes/group).
//    k_f1: new TT[32*264] staged before the first barrier (LDS 52.7KB).
//    Revert trigger: do_f1 k_pw >= 47us.

#define NLAYER 4

// ws offsets in floats
#define OFF_H     0L                  // hb ushorts, floats [0, 16.8M)
#define OFF_A2    16777216L           // A2 bf16: 4.2M ush = 2.1M fl
#define OFF_XFP   18874368L           // 4 x 262144 fl x-partials (A2 gap)
#define OFF_YA    33554432L           // Y fp32 (4194304 fl)
#define OFF_XF    37748736L           // 262144 fl (reduced Xf)
#define OFF_TAB   38010880L           // 256 fl
#define OFF_O1W   38011136L           // o1 bf16: 2048 ush = 1024 fl
#define OFF_TRIG  38013184L           // 8192 ush = 4096 fl
#define OFF_WT    38017280L           // 16384 ush = 8192 fl
#define OFF_TRIGT 38025472L           // 8192 ush = 4096 fl
#define WS_FLOATS 38029568L

// F1 B-layout c-stride in ushorts (R23: 264 = 132 words, %32 = 4 -> 4-bank
// shift per c; 256 = 4 full wraps -> 8-way conflicts)
#define BSTR 264
// Trig LDS row stride in ushorts (R31: 36 = 18 words -> conflict-free)
#define TPAD 36
// TrigT LDS row stride in ushorts (R33: 264 = 132 words; 132%32=4 ->
// group (n+kq)%8, uniform 8 lanes/group = floor)
#define TTP 264

typedef __attribute__((ext_vector_type(8))) short short8;
typedef __attribute__((ext_vector_type(4))) float f32x4;

__device__ __forceinline__ unsigned short f2bf(float f) {
  unsigned int u = __float_as_uint(f);
  u += 0x7FFF + ((u >> 16) & 1);          // round-to-nearest-even
  return (unsigned short)(u >> 16);
}

__global__ void k_init(float* __restrict__ ws, const float* __restrict__ pw_w,
                       const float* __restrict__ o1_w) {
  float* costab = ws + OFF_TAB;
  unsigned short* o1wbf = (unsigned short*)(ws + OFF_O1W);
  unsigned short* trig = (unsigned short*)(ws + OFF_TRIG);
  unsigned short* wt = (unsigned short*)(ws + OFF_WT);
  unsigned short* trigT = (unsigned short*)(ws + OFF_TRIGT);
  int t = blockIdx.x * blockDim.x + threadIdx.x;
  int stride = gridDim.x * blockDim.x;
  for (int m = t; m < 256; m += stride)
    costab[m] = (float)cos((double)m * (3.14159265358979323846 / 128.0));
  for (int idx = t; idx < 32 * 64; idx += stride)
    o1wbf[idx] = f2bf(o1_w[idx]);               // [o][c]
  for (int idx = t; idx < 256 * 32; idx += stride) {
    int y = idx >> 5, k = idx & 31;
    int mm = ((k & 15) * y) & 255;
    double ang = (double)mm * (3.14159265358979323846 / 128.0);
    double v = (k < 16) ? cos(ang) : sin(ang);
    trig[idx] = f2bf((float)v);
  }
  for (int idx = t; idx < 32 * 256; idx += stride) {   // trigT[r][y]
    int r = idx >> 8, y = idx & 255;
    int mm = ((r & 15) * y) & 255;
    double ang = (double)mm * (3.14159265358979323846 / 128.0);
    double v = (r < 16) ? cos(ang) : sin(ang);
    trigT[idx] = f2bf((float)v);
  }
  for (int idx = t; idx < NLAYER * 64 * 64; idx += stride)
    wt[idx] = f2bf(pw_w[idx]);                  // [l][o][c]
}

// F1 + input conv (R20 fused). Block = one (b,x) row.
// R33: trigT staged to TT (TTP rows) before the first barrier; MFMA A-frags
// read LDS instead of in-loop global.
__global__ void __launch_bounds__(256) k_f1(const float* __restrict__ x,
                                            const float* __restrict__ in_w,
                                            const float* __restrict__ in_b,
                                            const unsigned short* __restrict__ trigT,
                                            unsigned short* __restrict__ hb,
                                            float* __restrict__ Y) {
  __shared__ unsigned short St[64 * BSTR];
  __shared__ unsigned short TT[32 * TTP];      // 16.9 KB (R33)
  __shared__ float X0[256], X1[256];
  int t = threadIdx.x;
  long row = blockIdx.x;
  long b = row >> 8, xr = row & 255;
  const float* xb = x + b * 131072 + (xr << 8);
  X0[t] = xb[t];
  X1[t] = xb[65536 + t];
  #pragma unroll
  for (int k = 0; k < 4; ++k) {
    int idx8 = t + (k << 8);                   // [0,1024) trigT 8-chunks
    short8 v = *(const short8*)(trigT + (idx8 << 3));
    int rr = idx8 >> 5, sl = idx8 & 31;
    *(short8*)(&TT[rr * TTP + (sl << 3)]) = v;
  }
  int c0 = (t & 7) << 3;                       // fixed 8-channel group
  float wv[16], bv[8];
  #pragma unroll
  for (int e = 0; e < 8; ++e) {
    wv[2 * e]     = in_w[(c0 + e) * 2];
    wv[2 * e + 1] = in_w[(c0 + e) * 2 + 1];
    bv[e]         = in_b[c0 + e];
  }
  __syncthreads();
  unsigned short* hrow = hb + (row << 14);
  #pragma unroll
  for (int kk = 0; kk < 8; ++kk) {
    int idx8 = t + (kk << 8);                  // (y, c-group)
    int y = idx8 >> 3;
    float x0 = X0[y], x1 = X1[y];
    int yb = y >> 3, y7 = y & 7;
    short8 v;
    #pragma unroll
    for (int e = 0; e < 8; ++e) {
      int c = c0 + e;
      unsigned short hv = f2bf(bv[e] + wv[2 * e] * x0 + wv[2 * e + 1] * x1);
      v[e] = (short)hv;
      St[c * BSTR + (((yb ^ (c >> 3)) & 31) << 3) + y7] = hv;
    }
    *(short8*)(hrow + (idx8 << 3)) = v;
  }
  __syncthreads();
  int lane = t & 63;
  int wid = t >> 6;
  int kq = lane >> 4, n = lane & 15;
  #pragma unroll
  for (int pp = 0; pp < 2; ++pp) {
    int p = wid + (pp << 2);
    int mt = p & 1, nt = p >> 1;               // mt: 0=cos/Yr, 1=sin/Yi
    int trow = (mt << 4) + n;                  // A: m = lane&15
    int c = (nt << 4) + n;                     // B: n = lane&15
    const unsigned short* abase = &TT[trow * TTP + (kq << 3)];
    f32x4 acc = {0.0f, 0.0f, 0.0f, 0.0f};
    #pragma unroll
    for (int k0 = 0; k0 < 8; ++k0) {
      short8 af = *(const short8*)(abase + (k0 << 5));
      int yb = (k0 << 2) + kq;
      short8 bf = *(const short8*)(&St[c * BSTR + (((yb ^ (c >> 3)) & 31) << 3)]);
      acc = __builtin_amdgcn_mfma_f32_16x16x32_bf16(af, bf, acc, 0, 0, 0);
    }
    float sgn = mt ? -0.0625f : 0.0625f;       // Yi = -sum sin * h / 16
    float* yp = Y + (row << 11) + (kq << 9) + (c << 1) + mt;
    #pragma unroll
    for (int r = 0; r < 4; ++r)
      yp[r << 7] = acc[r] * sgn;               // ky = kq*4 + r
  }
}

// F2 with 4-way x-split (R17) + coop LDS staging (R29):
// grid = (s, b, ky, cq) [2048 blocks], thread = (c16, kx).
__global__ void __launch_bounds__(256) k_f2(const float* __restrict__ Y,
                                            const float* __restrict__ costab,
                                            float* __restrict__ Xfp) {
  __shared__ float T[256];
  __shared__ float2 YS[64][16];
  int t = threadIdx.x;
  T[t] = costab[t];
  int s = blockIdx.x >> 9;             // x-chunk [0,4)
  int blk = blockIdx.x & 511;
  int bk = blk >> 2;                   // b*16 + ky
  int b = bk >> 4, ky = bk & 15;
  int cq = blk & 3;
  int x0 = s << 6;
  // phase A: coop stage.  Per x-row: 32 consecutive floats (16 float2).
  const float* yb2 = Y + ((long)(b * 256 + x0)) * 2048 + ky * 128 + (cq << 5);
  #pragma unroll
  for (int k = 0; k < 4; ++k) {
    int idx = t + (k << 8);            // [0,1024) float2 slots
    int xx = idx >> 4, f2i = idx & 15;
    YS[xx][f2i] = *(const float2*)(yb2 + (long)xx * 2048 + (f2i << 1));
  }
  __syncthreads();
  // phase B: per-thread FMA from LDS.
  int c16 = t & 15;
  int c = (cq << 4) + c16;
  int kx = t >> 4;
  float ar = 0.0f, ai = 0.0f;
  int m = (kx * x0) & 255;
  #pragma unroll 4
  for (int x = 0; x < 64; ++x) {
    float2 v = YS[x][c16];
    float cv = T[m], sv = T[(m + 192) & 255];
    ar += v.x * cv + v.y * sv;         // (yr + i yi)(c - i s)
    ai += v.y * cv - v.x * sv;
    m = (m + kx) & 255;
  }
  float* o = Xfp + (long)s * 262144 + ((long)b * 64 + c) * 512 + (kx * 16 + ky) * 2;
  o[0] = ar * 0.0625f;
  o[1] = ai * 0.0625f;
}

// reduce the 4 x-partials -> Xf (R30: the sum is o-independent; doing it
// once here removes 4 loads from k_spec's serial chain).
__global__ void __launch_bounds__(256) k_xsum(const float* __restrict__ Xfp,
                                              float* __restrict__ Xf) {
  long i = ((long)blockIdx.x * 256 + threadIdx.x) << 2;
  f32x4 a = *(const f32x4*)(Xfp + i);
  f32x4 b = *(const f32x4*)(Xfp + 262144 + i);
  f32x4 c = *(const f32x4*)(Xfp + 524288 + i);
  f32x4 d = *(const f32x4*)(Xfp + 786432 + i);
  f32x4 ab = a + b;
  f32x4 cd = c + d;
  *(f32x4*)(Xf + i) = ab + cd;
}

// mode GEMM + I1 (R19: 512 threads; R30: reads pre-reduced Xf).
// block = b*64+o [512].
__global__ void __launch_bounds__(512) k_spec(const float* __restrict__ Xf,
                                              const float* __restrict__ wr,
                                              const float* __restrict__ wi,
                                              const float* __restrict__ costab,
                                              unsigned short* __restrict__ A2) {
  __shared__ float T[256];
  __shared__ float Gr[256], Gi[256];
  __shared__ float Pr[512], Pi[512];
  int t = threadIdx.x;
  if (t < 256) T[t] = costab[t];
  int b = blockIdx.x >> 6, o = blockIdx.x & 63;
  {
    int m = t & 255, h = t >> 8;               // h in {0,1}
    float gr = 0, gi = 0;
    const float* xb = Xf + (long)b * 32768 + m * 2 + (long)(h << 5) * 512;
    const float* wrb = wr + (long)o * 256 + m + (long)(h << 5) * 16384;
    const float* wib = wi + (long)o * 256 + m + (long)(h << 5) * 16384;
    for (int i = 0; i < 32; ++i) {
      float xr = xb[(long)i * 512], xi = xb[(long)i * 512 + 1];
      float wrv = wrb[(long)i * 16384], wiv = wib[(long)i * 16384];
      gr += xr * wrv - xi * wiv;
      gi += xr * wiv + xi * wrv;
    }
    Pr[t] = gr; Pi[t] = gi;
  }
  __syncthreads();
  if (t < 256) {
    Gr[t] = Pr[t] + Pr[t + 256];
    Gi[t] = Pi[t] + Pi[t + 256];
  }
  __syncthreads();
  int x = t & 255, kyh = t >> 8;               // kyh in {0,1}
  float ar[8], ai[8];
  #pragma unroll
  for (int r = 0; r < 8; ++r) { ar[r] = 0.0f; ai[r] = 0.0f; }
  for (int kx = 0; kx < 16; ++kx) {
    int mm = (kx * x) & 255;
    float cv = T[mm], sv = T[(mm + 192) & 255];
    int gb = (kx << 4) + (kyh << 3);
    #pragma unroll
    for (int r = 0; r < 8; ++r) {
      float gr = Gr[gb + r], gi = Gi[gb + r];
      ar[r] += gr * cv - gi * sv;      // (gr+i gi)(c + i s)
      ai[r] += gr * sv + gi * cv;
    }
  }
  unsigned short* ab = A2 + ((long)(b * 256 + x) << 11) + (o << 5) + (kyh << 3);
  short8 va, vb;
  #pragma unroll
  for (int r = 0; r < 8; ++r) {
    float sc = (kyh == 0 && r == 0) ? 0.00390625f : 0.0078125f;  // 1/256, 1/128
    va[r] = (short)f2bf(ar[r] * sc);
    vb[r] = (short)f2bf(-ai[r] * sc);
  }
  *(short8*)ab = va;
  *(short8*)(ab + 16) = vb;
}

// I2 + pointwise conv + GELU (in place on hb) FUSED with next layer's F1.
// Block = one full (b,x) row, 512 threads = 8 waves (proven 1-row form).
// Phase 0: stage 256x64 h tile -> S (XOR swizzle (c8^y)&7) AND trig
//          (16KB, TPAD rows) -> TS.
// Phase 1: A-frags from S, trig frags from TS; gelu -> hb + res regs.
// Phase 2a (do_f1): barrier, re-stage res into S (BSTR) AND trigT into
//          the now-dead TS (TTP rows) -- R33.
// Phase 2b: barrier, F1 MFMA (A-frags from TS-as-trigT) -> Y.
__global__ void __launch_bounds__(512) k_pw(unsigned short* __restrict__ hb,
                                            const unsigned short* __restrict__ A2,
                                            const unsigned short* __restrict__ Wt,
                                            const unsigned short* __restrict__ trig,
                                            const unsigned short* __restrict__ trigT,
                                            const float* __restrict__ pw_b,
                                            float* __restrict__ Y,
                                            int do_f1) {
  __shared__ unsigned short S[64 * BSTR];      // 33 KB; F1 B-tile reuses it
  __shared__ unsigned short TS[256 * TPAD];    // 18 KB trig cache (R31);
                                               // reused for trigT in 2b (R33)
  int t = threadIdx.x;
  long row = blockIdx.x;                       // (b,x) in [0,2048)
  int lane = t & 63;
  int wid = t >> 6;                            // 0..7
  int kq = lane >> 4, n = lane & 15;
  int half = wid >> 2;
  int o = ((wid & 3) << 4) + n;
  const unsigned short* wrow = Wt + (o << 6) + (kq << 3);
  short8 B0 = *(const short8*)(wrow);                               // c 0..31
  short8 B1 = *(const short8*)(wrow + 32);                          // c 32..63
  short8 B2 = *(const short8*)(A2 + (row << 11) + (o << 5) + (kq << 3)); // k'
  float bias = pw_b[o];
  // ---- phase 0: stage h row tile (XOR-swizzled) + trig (TPAD rows) ----
  const unsigned short* hrow = hb + (row << 14);
  #pragma unroll
  for (int k = 0; k < 4; ++k) {
    int idx8 = t + (k << 9);                   // [0,2048) ushort8 chunks
    short8 v = *(const short8*)(hrow + (idx8 << 3));
    int yy = idx8 >> 3, c8 = idx8 & 7;
    *(short8*)(&S[(yy << 6) + (((c8 ^ yy) & 7) << 3)]) = v;
  }
  #pragma unroll
  for (int k = 0; k < 2; ++k) {
    int idx8 = t + (k << 9);                   // [0,1024): trig 8-chunks
    short8 v = *(const short8*)(trig + (idx8 << 3));
    int yy = idx8 >> 2, sl = idx8 & 3;
    *(short8*)(&TS[yy * TPAD + (sl << 3)]) = v;
  }
  __syncthreads();                             // staging done before in-place writes
  // ---- phase 1: pw GEMM + gelu ----
  int s0 = (kq ^ n) & 7;                       // swizzled slot for c-group kq
  ushort4 res[8];
  #pragma unroll
  for (int i = 0; i < 8; ++i) {
    int m0 = i << 4;
    int yrow = (half << 7) + m0 + n;           // yrow&7 == n&7
    const unsigned short* srow = &S[yrow << 6];
    short8 a0 = *(const short8*)(srow + (s0 << 3));
    short8 a1 = *(const short8*)(srow + ((s0 ^ 4) << 3));
    short8 a2 = *(const short8*)(&TS[yrow * TPAD + (kq << 3)]);
    f32x4 acc = {0.0f, 0.0f, 0.0f, 0.0f};
    acc = __builtin_amdgcn_mfma_f32_16x16x32_bf16(a0, B0, acc, 0, 0, 0);
    acc = __builtin_amdgcn_mfma_f32_16x16x32_bf16(a1, B1, acc, 0, 0, 0);
    acc = __builtin_amdgcn_mfma_f32_16x16x32_bf16(a2, B2, acc, 0, 0, 0);
    float v0 = acc[0] + bias;
    v0 = 0.5f * v0 * (1.0f + erff(v0 * 0.70710678118654752f));
    float v1 = acc[1] + bias;
    v1 = 0.5f * v1 * (1.0f + erff(v1 * 0.70710678118654752f));
    float v2 = acc[2] + bias;
    v2 = 0.5f * v2 * (1.0f + erff(v2 * 0.70710678118654752f));
    float v3 = acc[3] + bias;
    v3 = 0.5f * v3 * (1.0f + erff(v3 * 0.70710678118654752f));
    res[i].x = f2bf(v0); res[i].y = f2bf(v1);
    res[i].z = f2bf(v2); res[i].w = f2bf(v3);
    int y0 = (half << 7) + m0 + (kq << 2);     // rows y0..y0+3, col o
    unsigned short* ob = hb + (row << 14) + ((long)y0 << 6) + o;
    ob[0] = res[i].x; ob[64] = res[i].y; ob[128] = res[i].z; ob[192] = res[i].w;
  }
  if (do_f1) {
    __syncthreads();                           // all phase-1 S & TS reads drained
    // ---- phase 2a: res -> S (F1 B-layout) + trigT -> TS (TTP rows) ----
    #pragma unroll
    for (int i = 0; i < 8; ++i) {
      int y0 = (half << 7) + (i << 4) + (kq << 2);
      int yb = y0 >> 3;
      *(ushort4*)(&S[o * BSTR + (((yb ^ (o >> 3)) & 31) << 3) + (y0 & 7)]) = res[i];
    }
    #pragma unroll
    for (int k = 0; k < 2; ++k) {
      int idx8 = t + (k << 9);                 // [0,1024): trigT 8-chunks
      short8 v = *(const short8*)(trigT + (idx8 << 3));
      int rr = idx8 >> 5, sl = idx8 & 31;
      *(short8*)(&TS[rr * TTP + (sl << 3)]) = v;   // max 8446 < 9216
    }
    __syncthreads();
    // ---- phase 2b: F1 MFMA (A-frags from TS-as-trigT) -> Y ----
    int mt = wid & 1, nt = wid >> 1;           // 8 waves = 2 mt x 4 nt
    int trow = (mt << 4) + n;
    int c = (nt << 4) + n;
    const unsigned short* abase = &TS[trow * TTP + (kq << 3)];
    f32x4 acc = {0.0f, 0.0f, 0.0f, 0.0f};
    #pragma unroll
    for (int k0 = 0; k0 < 8; ++k0) {
      short8 af = *(const short8*)(abase + (k0 << 5));
      int yb = (k0 << 2) + kq;
      short8 bf = *(const short8*)(&S[c * BSTR + (((yb ^ (c >> 3)) & 31) << 3)]);
      acc = __builtin_amdgcn_mfma_f32_16x16x32_bf16(af, bf, acc, 0, 0, 0);
    }
    float sgn = mt ? -0.0625f : 0.0625f;
    float* yp = Y + (row << 11) + (kq << 9) + (c << 1) + mt;
    #pragma unroll
    for (int r = 0; r < 4; ++r)
      yp[r << 7] = acc[r] * sgn;               // ky = kq*4 + r
  }
}

// output: hidden = H @ o1^T (bf16 MFMA, K=64), bias+gelu, then o2 dot via
// per-lane scale + butterfly shfl_xor over the quad's 16 columns.
__global__ void __launch_bounds__(256) k_out(const unsigned short* __restrict__ hb,
                                             const unsigned short* __restrict__ o1wbf,
                                             const float* __restrict__ o1_b,
                                             const float* __restrict__ o2_w,
                                             const float* __restrict__ o2_b,
                                             float* __restrict__ out) {
  __shared__ unsigned short S[128 * 88];
  int t = threadIdx.x;
  long row = blockIdx.x >> 1;                  // (b,x) in [0,2048)
  int half = blockIdx.x & 1;
  const unsigned short* hbase = hb + (row << 14) + (half << 13);
  #pragma unroll
  for (int k = 0; k < 4; ++k) {
    int idx8 = t + (k << 8);
    short8 v = *(const short8*)(hbase + (idx8 << 3));
    int yy = idx8 >> 3, c8 = idx8 & 7;
    *(short8*)(&S[yy * 88 + (c8 << 3)]) = v;
  }
  int lane = t & 63;
  int kq = lane >> 4;
  int n = lane & 15;
  int wid = t >> 6;                            // rows [32*wid, 32*wid+32)
  const unsigned short* w0 = o1wbf + (n << 6) + (kq << 3);         // o = n
  const unsigned short* w1 = o1wbf + ((n + 16) << 6) + (kq << 3);  // o = n+16
  short8 B0a = *(const short8*)(w0);
  short8 B0b = *(const short8*)(w0 + 32);
  short8 B1a = *(const short8*)(w1);
  short8 B1b = *(const short8*)(w1 + 32);
  float b0 = o1_b[n], b1 = o1_b[n + 16];
  float g0 = o2_w[n], g1 = o2_w[n + 16];
  float ob2 = o2_b[0];
  __syncthreads();
  float* outp = out + row * 256 + (half << 7);
  #pragma unroll
  for (int mt = 0; mt < 2; ++mt) {
    int m0 = (wid << 5) + (mt << 4);
    const unsigned short* srow = &S[(m0 + n) * 88 + (kq << 3)];
    short8 a0 = *(const short8*)(srow);
    short8 a1 = *(const short8*)(srow + 32);
    f32x4 c0 = {0.0f, 0.0f, 0.0f, 0.0f}, c1 = {0.0f, 0.0f, 0.0f, 0.0f};
    c0 = __builtin_amdgcn_mfma_f32_16x16x32_bf16(a0, B0a, c0, 0, 0, 0);
    c0 = __builtin_amdgcn_mfma_f32_16x16x32_bf16(a1, B0b, c0, 0, 0, 0);
    c1 = __builtin_amdgcn_mfma_f32_16x16x32_bf16(a0, B1a, c1, 0, 0, 0);
    c1 = __builtin_amdgcn_mfma_f32_16x16x32_bf16(a1, B1b, c1, 0, 0, 0);
    #pragma unroll
    for (int r = 0; r < 4; ++r) {
      float v0 = c0[r] + b0;
      v0 = 0.5f * v0 * (1.0f + erff(v0 * 0.70710678118654752f));
      float v1 = c1[r] + b1;
      v1 = 0.5f * v1 * (1.0f + erff(v1 * 0.70710678118654752f));
      float s = v0 * g0 + v1 * g1;
      s += __shfl_xor(s, 1);
      s += __shfl_xor(s, 2);
      s += __shfl_xor(s, 4);
      s += __shfl_xor(s, 8);
      if (n == 0) outp[m0 + (kq << 2) + r] = s + ob2;
    }
  }
}

extern "C" void kernel_launch(void* const* d_in, const int* in_sizes, int n_in,
                              void* d_out, int out_size, void* d_ws, size_t ws_size,
                              hipStream_t stream) {
  const float* x       = (const float*)d_in[0];
  const float* in_w    = (const float*)d_in[1];
  const float* in_b    = (const float*)d_in[2];
  const float* spec_wr = (const float*)d_in[3];
  const float* spec_wi = (const float*)d_in[4];
  const float* pw_w    = (const float*)d_in[5];
  const float* pw_b    = (const float*)d_in[6];
  const float* o1_w    = (const float*)d_in[7];
  const float* o1_b    = (const float*)d_in[8];
  const float* o2_w    = (const float*)d_in[9];
  const float* o2_b    = (const float*)d_in[10];
  float* ws = (float*)d_ws;
  unsigned short* hb = (unsigned short*)(ws + OFF_H);
  unsigned short* A2 = (unsigned short*)(ws + OFF_A2);
  float* Xfp    = ws + OFF_XFP;
  float* Y      = ws + OFF_YA;
  float* Xf     = ws + OFF_XF;
  float* costab = ws + OFF_TAB;
  unsigned short* o1wbf = (unsigned short*)(ws + OFF_O1W);
  unsigned short* trig = (unsigned short*)(ws + OFF_TRIG);
  unsigned short* wt   = (unsigned short*)(ws + OFF_WT);
  unsigned short* trigT = (unsigned short*)(ws + OFF_TRIGT);
  float* out = (float*)d_out;

  k_init<<<73, 256, 0, stream>>>(ws, pw_w, o1_w);
  k_f1<<<2048, 256, 0, stream>>>(x, in_w, in_b, trigT, hb, Y);  // +input conv
  for (int l = 0; l < NLAYER; ++l) {
    k_f2<<<2048, 256, 0, stream>>>(Y, costab, Xfp);
    k_xsum<<<256, 256, 0, stream>>>(Xfp, Xf);
    k_spec<<<512, 512, 0, stream>>>(Xf, spec_wr + (long)l * 1048576,
                                    spec_wi + (long)l * 1048576, costab, A2);
    k_pw<<<2048, 512, 0, stream>>>(hb, A2, wt + l * 4096, trig, trigT,
                                   pw_b + l * 64, Y, (l < NLAYER - 1) ? 1 : 0);
  }
  k_out<<<4096, 256, 0, stream>>>(hb, o1wbf, o1_b, o2_w, o2_b, out);
}

// Round 20
// 381.602 us; speedup vs baseline: 1.3231x; 1.0002x over previous
//
#include <hip/hip_runtime.h>
#include <math.h>

// FNO2d: B=8, CIN=2, COUT=1, W0=64, modes 16x16, NL=4, H=W=256
// h stored channels-last BF16: [B][H][W][64] ushort.
// Y  (F1 out, fp32): [B][H(x)][16ky][64c][2]
// Xfp (F2 out, fp32): 4 x-partials of Xf; Xf (fp32): [B][64c][256m][2]
// A2 (spec out, bf16): [B*256 rows][64o][32k']
// Trig  (bf16): [256y][32k'] (A-frags for k_pw I2)
// TrigT (bf16): [32 rows][256y] (A-frags for F1; rows 0-15 cos, 16-31 sin)
// k_f1 (layer 0 only) = input 1x1 conv + bf16 MFMA GEMM Y = TrigT @ H.
// k_pw = bf16 MFMA GEMM [H | Trig] @ [pw_w^T ; A2] + bias -> gelu -> hb,
//        FUSED with next layer's F1 via LDS (stage -> pw -> re-stage -> F1).
// k_out = bf16 MFMA GEMM (H @ o1^T) + gelu + cross-lane o2 dot.
//
// HARD-WON RULES:
//  - (R2/R3/R5) NEVER use min-waves arg of __launch_bounds__ with per-thread
//    accumulator arrays: backend spills to hit the VGPR tier.
//  - (R4/R6/R9) per-thread accs + uniform weight streaming via s_load is
//    latency-bound; keep weights in VGPR MFMA B-frags.
//  - (R11) grid must cover 256 CUs.  (R12) fuse pairs sharing a row tile.
//  - (R13) in-place kernels must stage the ENTIRE input tile (LDS or regs)
//    behind the first in-place write -- no direct global reads after.
//  - (R16) fast A-S-erf gelu REGRESSED (TRANS-pipe rcp+exp); erff kept.
//  - (R17) thin-grid latency kernels: k_f2 4-way x-split -> +19us.
//  - (R19) k_spec widened to 512 thr -> +7us.
//  - (R20) k_in->k_f1 fusion kept.
//  - (R21) k_pw 2-row/block pipeline REGRESSED (VGPR cliff); 1 row/block.
//  - (R22) containers throttle up to 25%; judge by clock-independent
//    counters (bytes, conflict counts) across containers.
//  - (R23) BSTR=264 pad: conflicts 7.34M -> 1.05M, k_pw 52.6 -> 49.6us.
//  - (R26) k_f2 8-way split doubled k_spec's reduce chain: REGRESSED.
//  - (R28) R27 "write amplification" was an arithmetic error; R12 base.
//  - (R29) k_f2 coop LDS staging: 463->444us.
//  - (R30) k_spec o-independent partial sum -> k_xsum: 444->405us.
//  - (R31) k_pw phase-1 trig -> LDS (TPAD=36): 405->401us.
//  - (R33) k_pw phase-2b + k_f1 trigT -> LDS (TTP=264, TS reuse):
//    401->382us; k_pw now below the 41us harness memsets in top-5.
//    Four wins from the same audit: NO global loads inside
//    latency-exposed serial/MFMA loops.
//  - (R34, this round) k_spec is the last thin-grid chain: 512thr x 512blk
//    = 16 waves/CU.  Widen to 1024 thr (32 waves/CU, full occupancy):
//    part A 4-way i-split (16-iter chain, pairwise-tree reduce), part B
//    4 ky/thread (ushort4 stores).  fp32 reassoc only (2x32 -> 4x16).

#define NLAYER 4

// ws offsets in floats
#define OFF_H     0L                  // hb ushorts, floats [0, 16.8M)
#define OFF_A2    16777216L           // A2 bf16: 4.2M ush = 2.1M fl
#define OFF_XFP   18874368L           // 4 x 262144 fl x-partials (A2 gap)
#define OFF_YA    33554432L           // Y fp32 (4194304 fl)
#define OFF_XF    37748736L           // 262144 fl (reduced Xf)
#define OFF_TAB   38010880L           // 256 fl
#define OFF_O1W   38011136L           // o1 bf16: 2048 ush = 1024 fl
#define OFF_TRIG  38013184L           // 8192 ush = 4096 fl
#define OFF_WT    38017280L           // 16384 ush = 8192 fl
#define OFF_TRIGT 38025472L           // 8192 ush = 4096 fl
#define WS_FLOATS 38029568L

// F1 B-layout c-stride in ushorts (R23: 264 = 132 words, %32 = 4 -> 4-bank
// shift per c; 256 = 4 full wraps -> 8-way conflicts)
#define BSTR 264
// Trig LDS row stride in ushorts (R31: 36 = 18 words -> conflict-free)
#define TPAD 36
// TrigT LDS row stride in ushorts (R33: 264 = 132 words; 132%32=4 ->
// group (n+kq)%8, uniform 8 lanes/group = floor)
#define TTP 264

typedef __attribute__((ext_vector_type(8))) short short8;
typedef __attribute__((ext_vector_type(4))) float f32x4;

__device__ __forceinline__ unsigned short f2bf(float f) {
  unsigned int u = __float_as_uint(f);
  u += 0x7FFF + ((u >> 16) & 1);          // round-to-nearest-even
  return (unsigned short)(u >> 16);
}

__global__ void k_init(float* __restrict__ ws, const float* __restrict__ pw_w,
                       const float* __restrict__ o1_w) {
  float* costab = ws + OFF_TAB;
  unsigned short* o1wbf = (unsigned short*)(ws + OFF_O1W);
  unsigned short* trig = (unsigned short*)(ws + OFF_TRIG);
  unsigned short* wt = (unsigned short*)(ws + OFF_WT);
  unsigned short* trigT = (unsigned short*)(ws + OFF_TRIGT);
  int t = blockIdx.x * blockDim.x + threadIdx.x;
  int stride = gridDim.x * blockDim.x;
  for (int m = t; m < 256; m += stride)
    costab[m] = (float)cos((double)m * (3.14159265358979323846 / 128.0));
  for (int idx = t; idx < 32 * 64; idx += stride)
    o1wbf[idx] = f2bf(o1_w[idx]);               // [o][c]
  for (int idx = t; idx < 256 * 32; idx += stride) {
    int y = idx >> 5, k = idx & 31;
    int mm = ((k & 15) * y) & 255;
    double ang = (double)mm * (3.14159265358979323846 / 128.0);
    double v = (k < 16) ? cos(ang) : sin(ang);
    trig[idx] = f2bf((float)v);
  }
  for (int idx = t; idx < 32 * 256; idx += stride) {   // trigT[r][y]
    int r = idx >> 8, y = idx & 255;
    int mm = ((r & 15) * y) & 255;
    double ang = (double)mm * (3.14159265358979323846 / 128.0);
    double v = (r < 16) ? cos(ang) : sin(ang);
    trigT[idx] = f2bf((float)v);
  }
  for (int idx = t; idx < NLAYER * 64 * 64; idx += stride)
    wt[idx] = f2bf(pw_w[idx]);                  // [l][o][c]
}

// F1 + input conv (R20 fused). Block = one (b,x) row.
// R33: trigT staged to TT (TTP rows) before the first barrier.
__global__ void __launch_bounds__(256) k_f1(const float* __restrict__ x,
                                            const float* __restrict__ in_w,
                                            const float* __restrict__ in_b,
                                            const unsigned short* __restrict__ trigT,
                                            unsigned short* __restrict__ hb,
                                            float* __restrict__ Y) {
  __shared__ unsigned short St[64 * BSTR];
  __shared__ unsigned short TT[32 * TTP];      // 16.9 KB (R33)
  __shared__ float X0[256], X1[256];
  int t = threadIdx.x;
  long row = blockIdx.x;
  long b = row >> 8, xr = row & 255;
  const float* xb = x + b * 131072 + (xr << 8);
  X0[t] = xb[t];
  X1[t] = xb[65536 + t];
  #pragma unroll
  for (int k = 0; k < 4; ++k) {
    int idx8 = t + (k << 8);                   // [0,1024) trigT 8-chunks
    short8 v = *(const short8*)(trigT + (idx8 << 3));
    int rr = idx8 >> 5, sl = idx8 & 31;
    *(short8*)(&TT[rr * TTP + (sl << 3)]) = v;
  }
  int c0 = (t & 7) << 3;                       // fixed 8-channel group
  float wv[16], bv[8];
  #pragma unroll
  for (int e = 0; e < 8; ++e) {
    wv[2 * e]     = in_w[(c0 + e) * 2];
    wv[2 * e + 1] = in_w[(c0 + e) * 2 + 1];
    bv[e]         = in_b[c0 + e];
  }
  __syncthreads();
  unsigned short* hrow = hb + (row << 14);
  #pragma unroll
  for (int kk = 0; kk < 8; ++kk) {
    int idx8 = t + (kk << 8);                  // (y, c-group)
    int y = idx8 >> 3;
    float x0 = X0[y], x1 = X1[y];
    int yb = y >> 3, y7 = y & 7;
    short8 v;
    #pragma unroll
    for (int e = 0; e < 8; ++e) {
      int c = c0 + e;
      unsigned short hv = f2bf(bv[e] + wv[2 * e] * x0 + wv[2 * e + 1] * x1);
      v[e] = (short)hv;
      St[c * BSTR + (((yb ^ (c >> 3)) & 31) << 3) + y7] = hv;
    }
    *(short8*)(hrow + (idx8 << 3)) = v;
  }
  __syncthreads();
  int lane = t & 63;
  int wid = t >> 6;
  int kq = lane >> 4, n = lane & 15;
  #pragma unroll
  for (int pp = 0; pp < 2; ++pp) {
    int p = wid + (pp << 2);
    int mt = p & 1, nt = p >> 1;               // mt: 0=cos/Yr, 1=sin/Yi
    int trow = (mt << 4) + n;                  // A: m = lane&15
    int c = (nt << 4) + n;                     // B: n = lane&15
    const unsigned short* abase = &TT[trow * TTP + (kq << 3)];
    f32x4 acc = {0.0f, 0.0f, 0.0f, 0.0f};
    #pragma unroll
    for (int k0 = 0; k0 < 8; ++k0) {
      short8 af = *(const short8*)(abase + (k0 << 5));
      int yb = (k0 << 2) + kq;
      short8 bf = *(const short8*)(&St[c * BSTR + (((yb ^ (c >> 3)) & 31) << 3)]);
      acc = __builtin_amdgcn_mfma_f32_16x16x32_bf16(af, bf, acc, 0, 0, 0);
    }
    float sgn = mt ? -0.0625f : 0.0625f;       // Yi = -sum sin * h / 16
    float* yp = Y + (row << 11) + (kq << 9) + (c << 1) + mt;
    #pragma unroll
    for (int r = 0; r < 4; ++r)
      yp[r << 7] = acc[r] * sgn;               // ky = kq*4 + r
  }
}

// F2 with 4-way x-split (R17) + coop LDS staging (R29):
// grid = (s, b, ky, cq) [2048 blocks], thread = (c16, kx).
__global__ void __launch_bounds__(256) k_f2(const float* __restrict__ Y,
                                            const float* __restrict__ costab,
                                            float* __restrict__ Xfp) {
  __shared__ float T[256];
  __shared__ float2 YS[64][16];
  int t = threadIdx.x;
  T[t] = costab[t];
  int s = blockIdx.x >> 9;             // x-chunk [0,4)
  int blk = blockIdx.x & 511;
  int bk = blk >> 2;                   // b*16 + ky
  int b = bk >> 4, ky = bk & 15;
  int cq = blk & 3;
  int x0 = s << 6;
  // phase A: coop stage.  Per x-row: 32 consecutive floats (16 float2).
  const float* yb2 = Y + ((long)(b * 256 + x0)) * 2048 + ky * 128 + (cq << 5);
  #pragma unroll
  for (int k = 0; k < 4; ++k) {
    int idx = t + (k << 8);            // [0,1024) float2 slots
    int xx = idx >> 4, f2i = idx & 15;
    YS[xx][f2i] = *(const float2*)(yb2 + (long)xx * 2048 + (f2i << 1));
  }
  __syncthreads();
  // phase B: per-thread FMA from LDS.
  int c16 = t & 15;
  int c = (cq << 4) + c16;
  int kx = t >> 4;
  float ar = 0.0f, ai = 0.0f;
  int m = (kx * x0) & 255;
  #pragma unroll 4
  for (int x = 0; x < 64; ++x) {
    float2 v = YS[x][c16];
    float cv = T[m], sv = T[(m + 192) & 255];
    ar += v.x * cv + v.y * sv;         // (yr + i yi)(c - i s)
    ai += v.y * cv - v.x * sv;
    m = (m + kx) & 255;
  }
  float* o = Xfp + (long)s * 262144 + ((long)b * 64 + c) * 512 + (kx * 16 + ky) * 2;
  o[0] = ar * 0.0625f;
  o[1] = ai * 0.0625f;
}

// reduce the 4 x-partials -> Xf (R30).
__global__ void __launch_bounds__(256) k_xsum(const float* __restrict__ Xfp,
                                              float* __restrict__ Xf) {
  long i = ((long)blockIdx.x * 256 + threadIdx.x) << 2;
  f32x4 a = *(const f32x4*)(Xfp + i);
  f32x4 b = *(const f32x4*)(Xfp + 262144 + i);
  f32x4 c = *(const f32x4*)(Xfp + 524288 + i);
  f32x4 d = *(const f32x4*)(Xfp + 786432 + i);
  f32x4 ab = a + b;
  f32x4 cd = c + d;
  *(f32x4*)(Xf + i) = ab + cd;
}

// mode GEMM + I1 (R34: 1024 threads, 32 waves/CU). block = b*64+o [512].
// Part A: thread (m, h in {0..3}): partial over i in [16h,16h+16) ->
//         pairwise-tree LDS reduce (P0+P1)+(P2+P3).
// Part B: thread (x, kyq in {0..3}): 16 kx x 4 ky FMA; ushort4 stores.
__global__ void __launch_bounds__(1024) k_spec(const float* __restrict__ Xf,
                                               const float* __restrict__ wr,
                                               const float* __restrict__ wi,
                                               const float* __restrict__ costab,
                                               unsigned short* __restrict__ A2) {
  __shared__ float T[256];
  __shared__ float Gr[256], Gi[256];
  __shared__ float Pr[1024], Pi[1024];
  int t = threadIdx.x;
  if (t < 256) T[t] = costab[t];
  int b = blockIdx.x >> 6, o = blockIdx.x & 63;
  {
    int m = t & 255, h = t >> 8;               // h in {0..3}
    float gr = 0, gi = 0;
    const float* xb = Xf + (long)b * 32768 + m * 2 + (long)(h << 4) * 512;
    const float* wrb = wr + (long)o * 256 + m + (long)(h << 4) * 16384;
    const float* wib = wi + (long)o * 256 + m + (long)(h << 4) * 16384;
    for (int i = 0; i < 16; ++i) {
      float xr = xb[(long)i * 512], xi = xb[(long)i * 512 + 1];
      float wrv = wrb[(long)i * 16384], wiv = wib[(long)i * 16384];
      gr += xr * wrv - xi * wiv;
      gi += xr * wiv + xi * wrv;
    }
    Pr[t] = gr; Pi[t] = gi;
  }
  __syncthreads();
  if (t < 256) {
    Gr[t] = (Pr[t] + Pr[t + 256]) + (Pr[t + 512] + Pr[t + 768]);
    Gi[t] = (Pi[t] + Pi[t + 256]) + (Pi[t + 512] + Pi[t + 768]);
  }
  __syncthreads();
  int x = t & 255, kyq = t >> 8;               // kyq in {0..3}
  float ar[4], ai[4];
  #pragma unroll
  for (int r = 0; r < 4; ++r) { ar[r] = 0.0f; ai[r] = 0.0f; }
  for (int kx = 0; kx < 16; ++kx) {
    int mm = (kx * x) & 255;
    float cv = T[mm], sv = T[(mm + 192) & 255];
    int gb = (kx << 4) + (kyq << 2);
    #pragma unroll
    for (int r = 0; r < 4; ++r) {
      float gr = Gr[gb + r], gi = Gi[gb + r];
      ar[r] += gr * cv - gi * sv;      // (gr+i gi)(c + i s)
      ai[r] += gr * sv + gi * cv;
    }
  }
  unsigned short* ab = A2 + ((long)(b * 256 + x) << 11) + (o << 5) + (kyq << 2);
  ushort4 va, vb;
  #pragma unroll
  for (int r = 0; r < 4; ++r) {
    float sc = (kyq == 0 && r == 0) ? 0.00390625f : 0.0078125f;  // 1/256, 1/128
    ((unsigned short*)&va)[r] = f2bf(ar[r] * sc);
    ((unsigned short*)&vb)[r] = f2bf(-ai[r] * sc);
  }
  *(ushort4*)ab = va;
  *(ushort4*)(ab + 16) = vb;
}

// I2 + pointwise conv + GELU (in place on hb) FUSED with next layer's F1.
// Block = one full (b,x) row, 512 threads = 8 waves (proven 1-row form).
// Phase 0: stage h -> S (XOR swizzle) + trig -> TS (TPAD rows, R31).
// Phase 1: A-frags from S/TS; gelu -> hb + res regs.
// Phase 2a (do_f1): barrier, res -> S (BSTR) + trigT -> dead TS (TTP, R33).
// Phase 2b: barrier, F1 MFMA -> Y.
__global__ void __launch_bounds__(512) k_pw(unsigned short* __restrict__ hb,
                                            const unsigned short* __restrict__ A2,
                                            const unsigned short* __restrict__ Wt,
                                            const unsigned short* __restrict__ trig,
                                            const unsigned short* __restrict__ trigT,
                                            const float* __restrict__ pw_b,
                                            float* __restrict__ Y,
                                            int do_f1) {
  __shared__ unsigned short S[64 * BSTR];      // 33 KB; F1 B-tile reuses it
  __shared__ unsigned short TS[256 * TPAD];    // 18 KB trig cache (R31);
                                               // reused for trigT in 2b (R33)
  int t = threadIdx.x;
  long row = blockIdx.x;                       // (b,x) in [0,2048)
  int lane = t & 63;
  int wid = t >> 6;                            // 0..7
  int kq = lane >> 4, n = lane & 15;
  int half = wid >> 2;
  int o = ((wid & 3) << 4) + n;
  const unsigned short* wrow = Wt + (o << 6) + (kq << 3);
  short8 B0 = *(const short8*)(wrow);                               // c 0..31
  short8 B1 = *(const short8*)(wrow + 32);                          // c 32..63
  short8 B2 = *(const short8*)(A2 + (row << 11) + (o << 5) + (kq << 3)); // k'
  float bias = pw_b[o];
  // ---- phase 0: stage h row tile (XOR-swizzled) + trig (TPAD rows) ----
  const unsigned short* hrow = hb + (row << 14);
  #pragma unroll
  for (int k = 0; k < 4; ++k) {
    int idx8 = t + (k << 9);                   // [0,2048) ushort8 chunks
    short8 v = *(const short8*)(hrow + (idx8 << 3));
    int yy = idx8 >> 3, c8 = idx8 & 7;
    *(short8*)(&S[(yy << 6) + (((c8 ^ yy) & 7) << 3)]) = v;
  }
  #pragma unroll
  for (int k = 0; k < 2; ++k) {
    int idx8 = t + (k << 9);                   // [0,1024): trig 8-chunks
    short8 v = *(const short8*)(trig + (idx8 << 3));
    int yy = idx8 >> 2, sl = idx8 & 3;
    *(short8*)(&TS[yy * TPAD + (sl << 3)]) = v;
  }
  __syncthreads();                             // staging done before in-place writes
  // ---- phase 1: pw GEMM + gelu ----
  int s0 = (kq ^ n) & 7;                       // swizzled slot for c-group kq
  ushort4 res[8];
  #pragma unroll
  for (int i = 0; i < 8; ++i) {
    int m0 = i << 4;
    int yrow = (half << 7) + m0 + n;           // yrow&7 == n&7
    const unsigned short* srow = &S[yrow << 6];
    short8 a0 = *(const short8*)(srow + (s0 << 3));
    short8 a1 = *(const short8*)(srow + ((s0 ^ 4) << 3));
    short8 a2 = *(const short8*)(&TS[yrow * TPAD + (kq << 3)]);
    f32x4 acc = {0.0f, 0.0f, 0.0f, 0.0f};
    acc = __builtin_amdgcn_mfma_f32_16x16x32_bf16(a0, B0, acc, 0, 0, 0);
    acc = __builtin_amdgcn_mfma_f32_16x16x32_bf16(a1, B1, acc, 0, 0, 0);
    acc = __builtin_amdgcn_mfma_f32_16x16x32_bf16(a2, B2, acc, 0, 0, 0);
    float v0 = acc[0] + bias;
    v0 = 0.5f * v0 * (1.0f + erff(v0 * 0.70710678118654752f));
    float v1 = acc[1] + bias;
    v1 = 0.5f * v1 * (1.0f + erff(v1 * 0.70710678118654752f));
    float v2 = acc[2] + bias;
    v2 = 0.5f * v2 * (1.0f + erff(v2 * 0.70710678118654752f));
    float v3 = acc[3] + bias;
    v3 = 0.5f * v3 * (1.0f + erff(v3 * 0.70710678118654752f));
    res[i].x = f2bf(v0); res[i].y = f2bf(v1);
    res[i].z = f2bf(v2); res[i].w = f2bf(v3);
    int y0 = (half << 7) + m0 + (kq << 2);     // rows y0..y0+3, col o
    unsigned short* ob = hb + (row << 14) + ((long)y0 << 6) + o;
    ob[0] = res[i].x; ob[64] = res[i].y; ob[128] = res[i].z; ob[192] = res[i].w;
  }
  if (do_f1) {
    __syncthreads();                           // all phase-1 S & TS reads drained
    // ---- phase 2a: res -> S (F1 B-layout) + trigT -> TS (TTP rows) ----
    #pragma unroll
    for (int i = 0; i < 8; ++i) {
      int y0 = (half << 7) + (i << 4) + (kq << 2);
      int yb = y0 >> 3;
      *(ushort4*)(&S[o * BSTR + (((yb ^ (o >> 3)) & 31) << 3) + (y0 & 7)]) = res[i];
    }
    #pragma unroll
    for (int k = 0; k < 2; ++k) {
      int idx8 = t + (k << 9);                 // [0,1024): trigT 8-chunks
      short8 v = *(const short8*)(trigT + (idx8 << 3));
      int rr = idx8 >> 5, sl = idx8 & 31;
      *(short8*)(&TS[rr * TTP + (sl << 3)]) = v;   // max 8446 < 9216
    }
    __syncthreads();
    // ---- phase 2b: F1 MFMA (A-frags from TS-as-trigT) -> Y ----
    int mt = wid & 1, nt = wid >> 1;           // 8 waves = 2 mt x 4 nt
    int trow = (mt << 4) + n;
    int c = (nt << 4) + n;
    const unsigned short* abase = &TS[trow * TTP + (kq << 3)];
    f32x4 acc = {0.0f, 0.0f, 0.0f, 0.0f};
    #pragma unroll
    for (int k0 = 0; k0 < 8; ++k0) {
      short8 af = *(const short8*)(abase + (k0 << 5));
      int yb = (k0 << 2) + kq;
      short8 bf = *(const short8*)(&S[c * BSTR + (((yb ^ (c >> 3)) & 31) << 3)]);
      acc = __builtin_amdgcn_mfma_f32_16x16x32_bf16(af, bf, acc, 0, 0, 0);
    }
    float sgn = mt ? -0.0625f : 0.0625f;
    float* yp = Y + (row << 11) + (kq << 9) + (c << 1) + mt;
    #pragma unroll
    for (int r = 0; r < 4; ++r)
      yp[r << 7] = acc[r] * sgn;               // ky = kq*4 + r
  }
}

// output: hidden = H @ o1^T (bf16 MFMA, K=64), bias+gelu, then o2 dot via
// per-lane scale + butterfly shfl_xor over the quad's 16 columns.
__global__ void __launch_bounds__(256) k_out(const unsigned short* __restrict__ hb,
                                             const unsigned short* __restrict__ o1wbf,
                                             const float* __restrict__ o1_b,
                                             const float* __restrict__ o2_w,
                                             const float* __restrict__ o2_b,
                                             float* __restrict__ out) {
  __shared__ unsigned short S[128 * 88];
  int t = threadIdx.x;
  long row = blockIdx.x >> 1;                  // (b,x) in [0,2048)
  int half = blockIdx.x & 1;
  const unsigned short* hbase = hb + (row << 14) + (half << 13);
  #pragma unroll
  for (int k = 0; k < 4; ++k) {
    int idx8 = t + (k << 8);
    short8 v = *(const short8*)(hbase + (idx8 << 3));
    int yy = idx8 >> 3, c8 = idx8 & 7;
    *(short8*)(&S[yy * 88 + (c8 << 3)]) = v;
  }
  int lane = t & 63;
  int kq = lane >> 4;
  int n = lane & 15;
  int wid = t >> 6;                            // rows [32*wid, 32*wid+32)
  const unsigned short* w0 = o1wbf + (n << 6) + (kq << 3);         // o = n
  const unsigned short* w1 = o1wbf + ((n + 16) << 6) + (kq << 3);  // o = n+16
  short8 B0a = *(const short8*)(w0);
  short8 B0b = *(const short8*)(w0 + 32);
  short8 B1a = *(const short8*)(w1);
  short8 B1b = *(const short8*)(w1 + 32);
  float b0 = o1_b[n], b1 = o1_b[n + 16];
  float g0 = o2_w[n], g1 = o2_w[n + 16];
  float ob2 = o2_b[0];
  __syncthreads();
  float* outp = out + row * 256 + (half << 7);
  #pragma unroll
  for (int mt = 0; mt < 2; ++mt) {
    int m0 = (wid << 5) + (mt << 4);
    const unsigned short* srow = &S[(m0 + n) * 88 + (kq << 3)];
    short8 a0 = *(const short8*)(srow);
    short8 a1 = *(const short8*)(srow + 32);
    f32x4 c0 = {0.0f, 0.0f, 0.0f, 0.0f}, c1 = {0.0f, 0.0f, 0.0f, 0.0f};
    c0 = __builtin_amdgcn_mfma_f32_16x16x32_bf16(a0, B0a, c0, 0, 0, 0);
    c0 = __builtin_amdgcn_mfma_f32_16x16x32_bf16(a1, B0b, c0, 0, 0, 0);
    c1 = __builtin_amdgcn_mfma_f32_16x16x32_bf16(a0, B1a, c1, 0, 0, 0);
    c1 = __builtin_amdgcn_mfma_f32_16x16x32_bf16(a1, B1b, c1, 0, 0, 0);
    #pragma unroll
    for (int r = 0; r < 4; ++r) {
      float v0 = c0[r] + b0;
      v0 = 0.5f * v0 * (1.0f + erff(v0 * 0.70710678118654752f));
      float v1 = c1[r] + b1;
      v1 = 0.5f * v1 * (1.0f + erff(v1 * 0.70710678118654752f));
      float s = v0 * g0 + v1 * g1;
      s += __shfl_xor(s, 1);
      s += __shfl_xor(s, 2);
      s += __shfl_xor(s, 4);
      s += __shfl_xor(s, 8);
      if (n == 0) outp[m0 + (kq << 2) + r] = s + ob2;
    }
  }
}

extern "C" void kernel_launch(void* const* d_in, const int* in_sizes, int n_in,
                              void* d_out, int out_size, void* d_ws, size_t ws_size,
                              hipStream_t stream) {
  const float* x       = (const float*)d_in[0];
  const float* in_w    = (const float*)d_in[1];
  const float* in_b    = (const float*)d_in[2];
  const float* spec_wr = (const float*)d_in[3];
  const float* spec_wi = (const float*)d_in[4];
  const float* pw_w    = (const float*)d_in[5];
  const float* pw_b    = (const float*)d_in[6];
  const float* o1_w    = (const float*)d_in[7];
  const float* o1_b    = (const float*)d_in[8];
  const float* o2_w    = (const float*)d_in[9];
  const float* o2_b    = (const float*)d_in[10];
  float* ws = (float*)d_ws;
  unsigned short* hb = (unsigned short*)(ws + OFF_H);
  unsigned short* A2 = (unsigned short*)(ws + OFF_A2);
  float* Xfp    = ws + OFF_XFP;
  float* Y      = ws + OFF_YA;
  float* Xf     = ws + OFF_XF;
  float* costab = ws + OFF_TAB;
  unsigned short* o1wbf = (unsigned short*)(ws + OFF_O1W);
  unsigned short* trig = (unsigned short*)(ws + OFF_TRIG);
  unsigned short* wt   = (unsigned short*)(ws + OFF_WT);
  unsigned short* trigT = (unsigned short*)(ws + OFF_TRIGT);
  float* out = (float*)d_out;

  k_init<<<73, 256, 0, stream>>>(ws, pw_w, o1_w);
  k_f1<<<2048, 256, 0, stream>>>(x, in_w, in_b, trigT, hb, Y);  // +input conv
  for (int l = 0; l < NLAYER; ++l) {
    k_f2<<<2048, 256, 0, stream>>>(Y, costab, Xfp);
    k_xsum<<<256, 256, 0, stream>>>(Xfp, Xf);
    k_spec<<<512, 1024, 0, stream>>>(Xf, spec_wr + (long)l * 1048576,
                                     spec_wi + (long)l * 1048576, costab, A2);
    k_pw<<<2048, 512, 0, stream>>>(hb, A2, wt + l * 4096, trig, trigT,
                                   pw_b + l * 64, Y, (l < NLAYER - 1) ? 1 : 0);
  }
  k_out<<<4096, 256, 0, stream>>>(hb, o1wbf, o1_b, o2_w, o2_b, out);
}